// Round 7
// baseline (15432.339 us; speedup 1.0000x reference)
//
#include <hip/hip_runtime.h>
#include <math.h>

namespace {

constexpr int N = 20000;
constexpr int E = 320000;
constexpr int EH = E / 2;          // chunk size (edges)
constexpr int C = 32;
constexpr int S = 9;
constexpr int Z = 10;
constexpr int G = 16;
constexpr int NB = 8;
constexpr int H = 64;
constexpr int CS = C * S;          // 288
constexpr float RMAX = 5.0f;
constexpr float PI_F = 3.14159265358979323846f;
constexpr float C1 = 1.7320508075688772f;   // sqrt(3)
constexpr float C2 = 3.8729833462074170f;   // sqrt(15)
constexpr float C3 = 1.1180339887498949f;   // sqrt(5)/2
constexpr float BESS_A = 0.6324555320336759f; // sqrt(2/5)

__device__ __forceinline__ float sigm(float x) { return 1.0f / (1.0f + __expf(-x)); }
__device__ __forceinline__ unsigned short f2bf(float f) {
    unsigned int u = __float_as_uint(f);
    unsigned int r = (u + 0x7FFFu + ((u >> 16) & 1u)) >> 16;
    return (unsigned short)r;
}
__device__ __forceinline__ float bf2f(unsigned short us) {
    return __uint_as_float(((unsigned int)us) << 16);
}

// ---------------- node-level kernels (unchanged) ----------------

__global__ void k_node_init(const float* __restrict__ attrs, const float* __restrict__ ae,
                            const float* __restrict__ Wemb, const int* __restrict__ batch,
                            int* __restrict__ sp_out, float* __restrict__ ne0,
                            float* __restrict__ h0, float* __restrict__ e0g) {
    int n = blockIdx.x * blockDim.x + threadIdx.x;
    if (n >= N) return;
    int sp = 0;
#pragma unroll
    for (int z = 0; z < Z; ++z)
        if (attrs[n * Z + z] > 0.5f) sp = z;
    sp_out[n] = sp;
    float e = ae[sp];
    ne0[n] = e;
    atomicAdd(&e0g[batch[n]], e);
#pragma unroll
    for (int c = 0; c < C; ++c) h0[n * C + c] = Wemb[sp * C + c];
}

__global__ void k_matmul_CC(const float* __restrict__ hin, const float* __restrict__ W,
                            float* __restrict__ hout) {
    int t = blockIdx.x * blockDim.x + threadIdx.x;
    if (t >= N * C) return;
    int n = t / C, d = t % C;
    float acc = 0.f;
#pragma unroll
    for (int c = 0; c < C; ++c) acc += hin[n * C + c] * W[c * C + d];
    hout[t] = acc;
}

__global__ void k_msg(const float* __restrict__ msum, const float* __restrict__ Wlin,
                      float* __restrict__ msg) {
    int t = blockIdx.x * blockDim.x + threadIdx.x;
    if (t >= N * C) return;
    int n = t / C, d = t % C;
    float acc = 0.f;
    for (int k = 0; k < CS; ++k) acc += msum[(size_t)n * CS + k] * Wlin[k * C + d];
    msg[t] = acc * (1.0f / 16.0f);
}

template <int WRITE_H>
__global__ void k_node_h(const float* __restrict__ msg, const float* __restrict__ hin,
                         const int* __restrict__ sp_arr, const float* __restrict__ Wprod,
                         const float* __restrict__ Wskip, const float* __restrict__ Wread,
                         float* __restrict__ hout_ws, float* __restrict__ es,
                         float* __restrict__ feats_out) {
    int n = blockIdx.x * blockDim.x + threadIdx.x;
    if (n >= N) return;
    int sp = sp_arr[n];
    float m[C], hi[C];
#pragma unroll
    for (int c = 0; c < C; ++c) { m[c] = msg[n * C + c]; hi[c] = hin[n * C + c]; }
    const float* Wsk = Wskip + (size_t)sp * C * C;
    float esum = 0.f;
    for (int d = 0; d < C; ++d) {
        float acc = 0.f;
#pragma unroll
        for (int c = 0; c < C; ++c) acc += m[c] * Wprod[c * C + d] + hi[c] * Wsk[c * C + d];
        esum += acc * Wread[d];
        if constexpr (WRITE_H) hout_ws[n * C + d] = acc;
        feats_out[(size_t)n * (2 * C) + d] = acc;
    }
    es[n] += esum;
}

__global__ void k_finalize(const float* __restrict__ ne0, const float* __restrict__ es,
                           const float* __restrict__ scale_p, const float* __restrict__ shift_p,
                           const int* __restrict__ batch, float* __restrict__ node_energy_out,
                           float* __restrict__ ieg) {
    int n = blockIdx.x * blockDim.x + threadIdx.x;
    if (n >= N) return;
    float nies = scale_p[0] * es[n] + shift_p[0];
    node_energy_out[n] = ne0[n] + nies;
    atomicAdd(&ieg[batch[n]], nies);
}

__global__ void k_graph(const float* __restrict__ e0g, const float* __restrict__ ieg,
                        float* __restrict__ tot_out, float* __restrict__ inter_out) {
    int g = threadIdx.x;
    if (g < G) { tot_out[g] = e0g[g] + ieg[g]; inter_out[g] = ieg[g]; }
}

__global__ void k_const1(const float* __restrict__ Wr1, const float* __restrict__ Wprod1,
                         const float* __restrict__ Wlin1, const float* __restrict__ Wskip1,
                         const float* __restrict__ scale_p, float* __restrict__ gms1,
                         float* __restrict__ gskip1) {
    int t = threadIdx.x;
    float sc = scale_p[0];
    if (t < CS) {
        float acc = 0.f;
        for (int d = 0; d < C; ++d) {
            float gm = 0.f;
#pragma unroll
            for (int d2 = 0; d2 < C; ++d2) gm += Wr1[d2] * Wprod1[d * C + d2];
            acc += gm * Wlin1[t * C + d];
        }
        gms1[t] = sc * acc * (1.0f / 16.0f);
    }
    if (t < Z * C) {
        int z = t / C, c = t % C;
        float acc = 0.f;
#pragma unroll
        for (int d = 0; d < C; ++d) acc += Wskip1[(z * C + c) * C + d] * Wr1[d];
        gskip1[t] = sc * acc;
    }
}

__global__ void k_gh1(const float* __restrict__ Wr0, const float* __restrict__ gskip1,
                      const int* __restrict__ sp_arr, const float* __restrict__ ghu1,
                      const float* __restrict__ Wup1, const float* __restrict__ scale_p,
                      float* __restrict__ gh1) {
    int t = blockIdx.x * blockDim.x + threadIdx.x;
    if (t >= N * C) return;
    int n = t / C, c = t % C;
    float acc = scale_p[0] * Wr0[c] + gskip1[sp_arr[n] * C + c];
#pragma unroll
    for (int d = 0; d < C; ++d) acc += ghu1[n * C + d] * Wup1[c * C + d];
    gh1[t] = acc;
}

__global__ void k_gmsg(const float* __restrict__ gh, const float* __restrict__ Wprod,
                       float* __restrict__ gmsg) {
    int t = blockIdx.x * blockDim.x + threadIdx.x;
    if (t >= N * C) return;
    int n = t / C, d = t % C;
    float acc = 0.f;
#pragma unroll
    for (int d2 = 0; d2 < C; ++d2) acc += gh[n * C + d2] * Wprod[d * C + d2];
    gmsg[t] = acc;
}

__global__ void k_gmsum(const float* __restrict__ gmsg, const float* __restrict__ Wlin,
                        float* __restrict__ gms) {
    int t = blockIdx.x * blockDim.x + threadIdx.x;
    if (t >= N * CS) return;
    int n = t / CS, k = t % CS;
    float acc = 0.f;
#pragma unroll
    for (int d = 0; d < C; ++d) acc += gmsg[n * C + d] * Wlin[k * C + d];
    gms[t] = acc * (1.0f / 16.0f);
}

// ---------------- CSR build (receiver-sorted) ----------------

__global__ void k_csr_count(const int* __restrict__ eidx, int* __restrict__ cnt) {
    int e = blockIdx.x * 256 + threadIdx.x;
    if (e >= E) return;
    atomicAdd(&cnt[eidx[E + e]], 1);
}

__global__ __launch_bounds__(1024) void k_csr_scan(const int* __restrict__ cnt,
                                                   int* __restrict__ rowstart,
                                                   int* __restrict__ pos) {
    __shared__ int part[1024];
    int t = threadIdx.x;
    const int CHUNK = 20;
    int base = t * CHUNK;
    int sum = 0;
    for (int i = 0; i < CHUNK; ++i) {
        int idx = base + i;
        if (idx < N) sum += cnt[idx];
    }
    part[t] = sum;
    __syncthreads();
    for (int off = 1; off < 1024; off <<= 1) {
        int v = (t >= off) ? part[t - off] : 0;
        __syncthreads();
        if (t >= off) part[t] += v;
        __syncthreads();
    }
    int run = (t == 0) ? 0 : part[t - 1];
    for (int i = 0; i < CHUNK; ++i) {
        int idx = base + i;
        if (idx < N) { rowstart[idx] = run; pos[idx] = run; run += cnt[idx]; }
    }
    if (t == 1023) rowstart[N] = run;
}

__global__ void k_csr_fill(const int* __restrict__ eidx, int* __restrict__ pos,
                           int* __restrict__ perm, int* __restrict__ snd_s,
                           int* __restrict__ rcv_s) {
    int e = blockIdx.x * 256 + threadIdx.x;
    if (e >= E) return;
    int rcv = eidx[E + e];
    int slot = atomicAdd(&pos[rcv], 1);
    perm[slot] = e;
    snd_s[slot] = eidx[e];
    rcv_s[slot] = rcv;
}

// ---------------- weight pre-transpose ----------------
// w2T[l][k*H+j] = Wm2[l][j*H+k];  w3T[l][cs*H+k] = Wm3[l][k*CS+cs]
__global__ void k_prep(const float* __restrict__ Wm2, const float* __restrict__ Wm3,
                       float* __restrict__ w2T, float* __restrict__ w3T) {
    int t = blockIdx.x * 256 + threadIdx.x;
    if (t < 2 * H * H) {
        int l = t / (H * H), r = t % (H * H);
        int k = r / H, j = r % H;
        w2T[t] = Wm2[l * H * H + j * H + k];
    }
    int u = t - 2 * H * H;
    if (u >= 0 && u < 2 * CS * H) {
        int l = u / (CS * H), r = u % (CS * H);
        int cs = r / H, k = r % H;
        w3T[u] = Wm3[l * H * CS + k * CS + cs];
    }
}

// ---------------- edge pipeline (all arrays in receiver-sorted index i) ----------------

// geometry: Ys[i][12] edge-major, EFs plane-major [b][i]
__global__ __launch_bounds__(256) void k_geom(
    const float* __restrict__ pos, const float* __restrict__ shifts,
    const int* __restrict__ perm, const int* __restrict__ snd_s,
    const int* __restrict__ rcv_s, float* __restrict__ Ys, float* __restrict__ EFs) {
    int i = blockIdx.x * 256 + threadIdx.x;
    int snd = snd_s[i], rcv = rcv_s[i], e = perm[i];
    float vx = pos[rcv * 3 + 0] - pos[snd * 3 + 0] + shifts[e * 3 + 0];
    float vy = pos[rcv * 3 + 1] - pos[snd * 3 + 1] + shifts[e * 3 + 1];
    float vz = pos[rcv * 3 + 2] - pos[snd * 3 + 2] + shifts[e * 3 + 2];
    float r = sqrtf(vx * vx + vy * vy + vz * vz + 1e-12f);
    float inv = 1.0f / r;
    float x = vx * inv, y = vy * inv, z = vz * inv;
    float* yr = Ys + (size_t)i * 12;
    yr[0] = 1.f;
    yr[1] = C1 * x;
    yr[2] = C1 * y;
    yr[3] = C1 * z;
    yr[4] = C2 * x * y;
    yr[5] = C2 * y * z;
    yr[6] = C3 * (3.f * z * z - 1.f);
    yr[7] = C2 * x * z;
    yr[8] = 0.5f * C2 * (x * x - y * y);
    yr[9] = 0.f; yr[10] = 0.f; yr[11] = 0.f;
    float ru = r * (1.0f / RMAX);
    float env = 0.f;
    if (ru < 1.f) {
        float u2 = ru * ru, u4 = u2 * u2, u6 = u4 * u2, u7 = u6 * ru, u8 = u7 * ru;
        env = 1.f - 28.f * u6 + 48.f * u7 - 21.f * u8;
    }
#pragma unroll
    for (int b = 0; b < NB; ++b) {
        float kb = (b + 1) * (PI_F / RMAX);
        EFs[b * E + i] = BESS_A * __sinf(kb * r) * inv * env;
    }
}

// fused radial-MLP + tpw GEMM for one edge chunk: tpw[i-c_lo][cs] (bf16) = silu-MLP(ef) @ W3
__global__ __launch_bounds__(256) void k_mlp_tpw(
    const float* __restrict__ EFs, const float* __restrict__ w1g,
    const float* __restrict__ w2Tg, const float* __restrict__ w3Tg,
    int c_lo, unsigned short* __restrict__ tpw) {
    __shared__ float w1[NB * H];                 // 2 KB
    __shared__ alignas(16) float w2t[H * H];     // 16 KB  [k][j]
    __shared__ alignas(16) float w3t[144 * H];   // 36.9 KB [cs_local][k]
    int tid = threadIdx.x;
    for (int idx = tid; idx < NB * H; idx += 256) w1[idx] = w1g[idx];
    {
        const float4* src = (const float4*)w2Tg;
        float4* dst = (float4*)w2t;
        for (int idx = tid; idx < H * H / 4; idx += 256) dst[idx] = src[idx];
    }
    __syncthreads();
    int i = c_lo + blockIdx.x * 256 + tid;
    float ef[NB];
#pragma unroll
    for (int b = 0; b < NB; ++b) ef[b] = EFs[b * E + i];
    float t1[H];
#pragma unroll
    for (int j = 0; j < H; ++j) {
        float zz = 0.f;
#pragma unroll
        for (int b = 0; b < NB; ++b) zz += ef[b] * w1[b * H + j];
        t1[j] = zz * sigm(zz);
    }
    float t2[H];
    for (int k = 0; k < H; ++k) {
        float s0 = 0.f, s1 = 0.f, s2 = 0.f, s3 = 0.f;
#pragma unroll
        for (int jj = 0; jj < 16; ++jj) {
            float4 w = *reinterpret_cast<const float4*>(&w2t[k * H + jj * 4]);
            s0 += t1[jj * 4 + 0] * w.x;
            s1 += t1[jj * 4 + 1] * w.y;
            s2 += t1[jj * 4 + 2] * w.z;
            s3 += t1[jj * 4 + 3] * w.w;
        }
        float zz = (s0 + s1) + (s2 + s3);
        t2[k] = zz * sigm(zz);
    }
    unsigned int* orow = (unsigned int*)(tpw + (size_t)(i - c_lo) * CS);
    for (int half = 0; half < 2; ++half) {
        __syncthreads();
        {
            const float4* src = (const float4*)(w3Tg + half * 144 * H);
            float4* dst = (float4*)w3t;
            for (int idx = tid; idx < 144 * H / 4; idx += 256) dst[idx] = src[idx];
        }
        __syncthreads();
        for (int csp = 0; csp < 72; ++csp) {
            int csl = csp * 2;
            float a0 = 0.f, a1 = 0.f;
#pragma unroll
            for (int k4 = 0; k4 < 16; ++k4) {
                float4 w0 = *reinterpret_cast<const float4*>(&w3t[csl * H + k4 * 4]);
                float4 w1v = *reinterpret_cast<const float4*>(&w3t[(csl + 1) * H + k4 * 4]);
                a0 += t2[k4 * 4 + 0] * w0.x + t2[k4 * 4 + 1] * w0.y
                    + t2[k4 * 4 + 2] * w0.z + t2[k4 * 4 + 3] * w0.w;
                a1 += t2[k4 * 4 + 0] * w1v.x + t2[k4 * 4 + 1] * w1v.y
                    + t2[k4 * 4 + 2] * w1v.z + t2[k4 * 4 + 3] * w1v.w;
            }
            orow[half * 72 + csp] = (unsigned int)f2bf(a0) | ((unsigned int)f2bf(a1) << 16);
        }
    }
}

// gather: wave per node, lane = cs-slot; contiguous sorted edges, no shfl/LDS.
__global__ __launch_bounds__(512) void k_gather(
    const int* __restrict__ rowstart, const int* __restrict__ snd_s,
    const float* __restrict__ hu, const unsigned short* __restrict__ tpw,
    const float* __restrict__ Ys, float* __restrict__ msum,
    int c_lo, int c_hi) {
    int tid = threadIdx.x;
    int wave = tid >> 6, lane = tid & 63;
    int n = blockIdx.x * 8 + wave;
    int i0 = rowstart[n], i1 = rowstart[n + 1];
    if (i0 < c_lo) i0 = c_lo;
    if (i1 > c_hi) i1 = c_hi;
    if (i0 >= i1) return;
    bool has4 = lane < 32;
    int cs4m = has4 ? lane + 256 : lane;
    const int ci0 = lane / 9,         si0 = lane % 9;
    const int ci1 = (lane + 64) / 9,  si1 = (lane + 64) % 9;
    const int ci2 = (lane + 128) / 9, si2 = (lane + 128) % 9;
    const int ci3 = (lane + 192) / 9, si3 = (lane + 192) % 9;
    const int ci4 = cs4m / 9,         si4 = cs4m % 9;
    float acc0 = 0.f, acc1 = 0.f, acc2 = 0.f, acc3 = 0.f, acc4 = 0.f;
    for (int i = i0; i < i1; ++i) {
        int snd = snd_s[i];
        const unsigned short* tr = tpw + (size_t)(i - c_lo) * CS;
        float t0 = bf2f(tr[lane]);
        float t1v = bf2f(tr[lane + 64]);
        float t2v = bf2f(tr[lane + 128]);
        float t3v = bf2f(tr[lane + 192]);
        float t4v = bf2f(tr[cs4m]);
        const float* yr = Ys + (size_t)i * 12;
        float y0 = yr[si0], y1 = yr[si1], y2 = yr[si2], y3 = yr[si3], y4 = yr[si4];
        const float* hr = hu + (size_t)snd * C;
        float h0 = hr[ci0], h1 = hr[ci1], h2 = hr[ci2], h3 = hr[ci3], h4 = hr[ci4];
        acc0 += h0 * y0 * t0;
        acc1 += h1 * y1 * t1v;
        acc2 += h2 * y2 * t2v;
        acc3 += h3 * y3 * t3v;
        acc4 += h4 * y4 * t4v;
    }
    float* mrow = msum + (size_t)n * CS;
    mrow[lane] += acc0;
    mrow[lane + 64] += acc1;
    mrow[lane + 128] += acc2;
    mrow[lane + 192] += acc3;
    if (has4) mrow[lane + 256] += acc4;
}

// fused backward per edge: recompute MLP, stream cs once producing gY/ghu/gt2,
// then gt1/gef/geometry/forces. No intermediate edge buffers.
template <bool L1>
__global__ __launch_bounds__(256) void k_bwd_fused(
    const float* __restrict__ pos, const float* __restrict__ shifts,
    const int* __restrict__ perm, const int* __restrict__ snd_s,
    const int* __restrict__ rcv_s, const float* __restrict__ EFs,
    const float* __restrict__ Ys, const float* __restrict__ w1g,
    const float* __restrict__ w2Tg, const float* __restrict__ w3Tg,
    const float* __restrict__ gm, const float* __restrict__ hu,
    float* __restrict__ ghu, float* __restrict__ forces) {
    __shared__ float w1[NB * H];
    __shared__ alignas(16) float w2t[H * H];
    __shared__ alignas(16) float w3t[144 * H];
    int tid = threadIdx.x;
    for (int idx = tid; idx < NB * H; idx += 256) w1[idx] = w1g[idx];
    {
        const float4* src = (const float4*)w2Tg;
        float4* dst = (float4*)w2t;
        for (int idx = tid; idx < H * H / 4; idx += 256) dst[idx] = src[idx];
    }
    __syncthreads();
    int i = blockIdx.x * 256 + tid;
    int snd = snd_s[i], rcv = rcv_s[i];

    float ef[NB];
#pragma unroll
    for (int b = 0; b < NB; ++b) ef[b] = EFs[b * E + i];
    float t1[H];
#pragma unroll
    for (int j = 0; j < H; ++j) {
        float zz = 0.f;
#pragma unroll
        for (int b = 0; b < NB; ++b) zz += ef[b] * w1[b * H + j];
        t1[j] = zz * sigm(zz);
    }
    float z2[H], t2[H];
    for (int k = 0; k < H; ++k) {
        float s0 = 0.f, s1 = 0.f, s2 = 0.f, s3 = 0.f;
#pragma unroll
        for (int jj = 0; jj < 16; ++jj) {
            float4 w = *reinterpret_cast<const float4*>(&w2t[k * H + jj * 4]);
            s0 += t1[jj * 4 + 0] * w.x;
            s1 += t1[jj * 4 + 1] * w.y;
            s2 += t1[jj * 4 + 2] * w.z;
            s3 += t1[jj * 4 + 3] * w.w;
        }
        float zz = (s0 + s1) + (s2 + s3);
        z2[k] = zz;
        t2[k] = zz * sigm(zz);
    }
    float ysr[S];
#pragma unroll
    for (int s = 0; s < S; ++s) ysr[s] = Ys[(size_t)i * 12 + s];

    float gY[S];
#pragma unroll
    for (int s = 0; s < S; ++s) gY[s] = 0.f;
    float gt2[H];
#pragma unroll
    for (int k = 0; k < H; ++k) gt2[k] = 0.f;

    const float* gmrow = L1 ? gm : (gm + (size_t)rcv * CS);
    for (int half = 0; half < 2; ++half) {
        __syncthreads();
        {
            const float4* src = (const float4*)(w3Tg + half * 144 * H);
            float4* dst = (float4*)w3t;
            for (int idx = tid; idx < 144 * H / 4; idx += 256) dst[idx] = src[idx];
        }
        __syncthreads();
        for (int cc = 0; cc < 16; ++cc) {
            int c = half * 16 + cc;
            float hv = hu[(size_t)snd * C + c];
            float ghc = 0.f;
#pragma unroll
            for (int s = 0; s < S; ++s) {
                int csl = cc * 9 + s;
                float gmv = gmrow[c * 9 + s];
                float yv = ysr[s];
                float p = gmv * hv;
                float gtw = p * yv;
                float tpwv = 0.f;
#pragma unroll
                for (int k4 = 0; k4 < 16; ++k4) {
                    float4 w = *reinterpret_cast<const float4*>(&w3t[csl * H + k4 * 4]);
                    tpwv += t2[k4 * 4 + 0] * w.x + t2[k4 * 4 + 1] * w.y
                          + t2[k4 * 4 + 2] * w.z + t2[k4 * 4 + 3] * w.w;
                    gt2[k4 * 4 + 0] += gtw * w.x;
                    gt2[k4 * 4 + 1] += gtw * w.y;
                    gt2[k4 * 4 + 2] += gtw * w.z;
                    gt2[k4 * 4 + 3] += gtw * w.w;
                }
                gY[s] += p * tpwv;
                ghc += gmv * yv * tpwv;
            }
            if (L1) atomicAdd(&ghu[(size_t)snd * C + c], ghc);
        }
    }

    // gt1 = sum_k gz2[k] * W2[j][k]
    float gt1[H];
#pragma unroll
    for (int j = 0; j < H; ++j) gt1[j] = 0.f;
    for (int k = 0; k < H; ++k) {
        float sg = sigm(z2[k]);
        float gz2 = gt2[k] * sg * (1.f + z2[k] * (1.f - sg));
#pragma unroll
        for (int jj = 0; jj < 16; ++jj) {
            float4 w = *reinterpret_cast<const float4*>(&w2t[k * H + jj * 4]);
            gt1[jj * 4 + 0] += gz2 * w.x;
            gt1[jj * 4 + 1] += gz2 * w.y;
            gt1[jj * 4 + 2] += gz2 * w.z;
            gt1[jj * 4 + 3] += gz2 * w.w;
        }
    }
    float gef[NB];
#pragma unroll
    for (int b = 0; b < NB; ++b) gef[b] = 0.f;
#pragma unroll
    for (int j = 0; j < H; ++j) {
        float z1 = 0.f;
#pragma unroll
        for (int b = 0; b < NB; ++b) z1 += ef[b] * w1[b * H + j];
        float sg = sigm(z1);
        float gz1 = gt1[j] * sg * (1.f + z1 * (1.f - sg));
#pragma unroll
        for (int b = 0; b < NB; ++b) gef[b] += gz1 * w1[b * H + j];
    }
    // geometry recompute + force chain
    int e = perm[i];
    float vx = pos[rcv * 3 + 0] - pos[snd * 3 + 0] + shifts[e * 3 + 0];
    float vy = pos[rcv * 3 + 1] - pos[snd * 3 + 1] + shifts[e * 3 + 1];
    float vz = pos[rcv * 3 + 2] - pos[snd * 3 + 2] + shifts[e * 3 + 2];
    float r = sqrtf(vx * vx + vy * vy + vz * vz + 1e-12f);
    float inv = 1.0f / r;
    float x = vx * inv, y = vy * inv, z = vz * inv;
    float ru = r * (1.0f / RMAX);
    float env = 0.f, denv_dr = 0.f;
    if (ru < 1.f) {
        float u2 = ru * ru, u4 = u2 * u2, u5 = u4 * ru, u6 = u5 * ru, u7 = u6 * ru, u8 = u7 * ru;
        env = 1.f - 28.f * u6 + 48.f * u7 - 21.f * u8;
        denv_dr = (-168.f * u5 + 336.f * u6 - 168.f * u7) * (1.0f / RMAX);
    }
    float gr = 0.f;
#pragma unroll
    for (int b = 0; b < NB; ++b) {
        float kb = (b + 1) * (PI_F / RMAX);
        float sb = __sinf(kb * r), cb = __cosf(kb * r);
        float bess = BESS_A * sb * inv;
        float dbess = BESS_A * (kb * cb - sb * inv) * inv;
        gr += gef[b] * (dbess * env + bess * denv_dr);
    }
    float gx = C1 * gY[1] + C2 * y * gY[4] + C2 * z * gY[7] + C2 * x * gY[8];
    float gy = C1 * gY[2] + C2 * x * gY[4] + C2 * z * gY[5] - C2 * y * gY[8];
    float gz = C1 * gY[3] + C2 * y * gY[5] + 6.f * C3 * z * gY[6] + C2 * x * gY[7];
    float dot = gx * x + gy * y + gz * z;
    float gvx = (gx - dot * x) * inv + gr * x;
    float gvy = (gy - dot * y) * inv + gr * y;
    float gvz = (gz - dot * z) * inv + gr * z;
    atomicAdd(&forces[snd * 3 + 0], gvx);
    atomicAdd(&forces[snd * 3 + 1], gvy);
    atomicAdd(&forces[snd * 3 + 2], gvz);
    atomicAdd(&forces[rcv * 3 + 0], -gvx);
    atomicAdd(&forces[rcv * 3 + 1], -gvy);
    atomicAdd(&forces[rcv * 3 + 2], -gvz);
}

} // namespace

extern "C" void kernel_launch(void* const* d_in, const int* in_sizes, int n_in,
                              void* d_out, int out_size, void* d_ws, size_t ws_size,
                              hipStream_t stream) {
    const float* pos    = (const float*)d_in[0];
    const float* attrs  = (const float*)d_in[1];
    const float* shifts = (const float*)d_in[2];
    const float* ae     = (const float*)d_in[3];
    const float* Wemb   = (const float*)d_in[4];
    const float* Wup    = (const float*)d_in[5];
    const float* Wm1    = (const float*)d_in[6];
    const float* Wm2    = (const float*)d_in[7];
    const float* Wm3    = (const float*)d_in[8];
    const float* Wlin   = (const float*)d_in[9];
    const float* Wskip  = (const float*)d_in[10];
    const float* Wprod  = (const float*)d_in[11];
    const float* Wread  = (const float*)d_in[12];
    const float* scale  = (const float*)d_in[13];
    const float* shiftp = (const float*)d_in[14];
    const int*   eidx   = (const int*)d_in[15];
    const int*   batch  = (const int*)d_in[16];

    float* out       = (float*)d_out;
    float* out_tot   = out;                     // G
    float* out_ne    = out + G;                 // N
    float* out_ie    = out + G + N;             // G
    float* out_F     = out + 2 * G + N;         // N*3
    float* out_feats = out + 2 * G + N + 3 * N; // N*2C

    char* w = (char*)d_ws;
    auto alloc = [&](size_t bytes) { void* p = (void*)w; w += (bytes + 255) & ~(size_t)255; return p; };
    int*   sp     = (int*)alloc((size_t)N * 4);
    float* ne0    = (float*)alloc((size_t)N * 4);
    float* es     = (float*)alloc((size_t)N * 4);
    float* e0g    = (float*)alloc((size_t)G * 4);
    float* ieg    = (float*)alloc((size_t)G * 4);
    float* h0     = (float*)alloc((size_t)N * C * 4);
    float* h1     = (float*)alloc((size_t)N * C * 4);
    float* hu0    = (float*)alloc((size_t)N * C * 4);
    float* hu1    = (float*)alloc((size_t)N * C * 4);
    float* msgb   = (float*)alloc((size_t)N * C * 4);
    float* ghu1   = (float*)alloc((size_t)N * C * 4);
    float* gh1    = (float*)alloc((size_t)N * C * 4);
    float* gms1   = (float*)alloc((size_t)CS * 4);
    float* gskip1 = (float*)alloc((size_t)Z * C * 4);
    int*   cnt    = (int*)alloc((size_t)N * 4);
    int*   rowst  = (int*)alloc((size_t)(N + 1) * 4);
    int*   posb   = (int*)alloc((size_t)N * 4);
    int*   perm   = (int*)alloc((size_t)E * 4);
    int*   snd_s  = (int*)alloc((size_t)E * 4);
    int*   rcv_s  = (int*)alloc((size_t)E * 4);
    float* msum   = (float*)alloc((size_t)N * CS * 4);     // fwd msgsum / bwd gm0
    float* EFs    = (float*)alloc((size_t)NB * E * 4);
    float* Ys     = (float*)alloc((size_t)E * 12 * 4);
    float* w2T    = (float*)alloc((size_t)2 * H * H * 4);
    float* w3T    = (float*)alloc((size_t)2 * CS * H * 4);
    unsigned short* tpw = (unsigned short*)alloc((size_t)EH * CS * 2);  // 92.2 MB

    hipMemsetAsync(es, 0, (size_t)N * 4, stream);
    hipMemsetAsync(e0g, 0, (size_t)G * 4, stream);
    hipMemsetAsync(ieg, 0, (size_t)G * 4, stream);
    hipMemsetAsync(ghu1, 0, (size_t)N * C * 4, stream);
    hipMemsetAsync(cnt, 0, (size_t)N * 4, stream);
    hipMemsetAsync(out_F, 0, (size_t)N * 3 * 4, stream);

    dim3 b256(256);
    int gn   = (N + 255) / 256;
    int gnc  = (N * C + 255) / 256;
    int gncs = (N * CS + 255) / 256;
    int ge   = E / 256;                 // 1250, exact
    int geh  = EH / 256;                // 625, exact
    int gg   = N / 8;                   // 2500, exact

    // CSR build (receiver-sorted)
    k_csr_count<<<ge, b256, 0, stream>>>(eidx, cnt);
    k_csr_scan<<<1, 1024, 0, stream>>>(cnt, rowst, posb);
    k_csr_fill<<<ge, b256, 0, stream>>>(eidx, posb, perm, snd_s, rcv_s);

    k_node_init<<<gn, b256, 0, stream>>>(attrs, ae, Wemb, batch, sp, ne0, h0, e0g);
    k_prep<<<176, b256, 0, stream>>>(Wm2, Wm3, w2T, w3T);
    k_geom<<<ge, b256, 0, stream>>>(pos, shifts, perm, snd_s, rcv_s, Ys, EFs);

    // ---- layer 0 forward ----
    k_matmul_CC<<<gnc, b256, 0, stream>>>(h0, Wup, hu0);
    hipMemsetAsync(msum, 0, (size_t)N * CS * 4, stream);
    for (int cchunk = 0; cchunk < 2; ++cchunk) {
        int lo = cchunk * EH, hi = lo + EH;
        k_mlp_tpw<<<geh, b256, 0, stream>>>(EFs, Wm1, w2T, w3T, lo, tpw);
        k_gather<<<gg, 512, 0, stream>>>(rowst, snd_s, hu0, tpw, Ys, msum, lo, hi);
    }
    k_msg<<<gnc, b256, 0, stream>>>(msum, Wlin, msgb);
    k_node_h<1><<<gn, b256, 0, stream>>>(msgb, h0, sp, Wprod, Wskip, Wread, h1, es, out_feats);

    // ---- layer 1 forward ----
    k_matmul_CC<<<gnc, b256, 0, stream>>>(h1, Wup + C * C, hu1);
    hipMemsetAsync(msum, 0, (size_t)N * CS * 4, stream);
    for (int cchunk = 0; cchunk < 2; ++cchunk) {
        int lo = cchunk * EH, hi = lo + EH;
        k_mlp_tpw<<<geh, b256, 0, stream>>>(EFs, Wm1 + NB * H, w2T + H * H, w3T + CS * H,
                                            lo, tpw);
        k_gather<<<gg, 512, 0, stream>>>(rowst, snd_s, hu1, tpw, Ys, msum, lo, hi);
    }
    k_msg<<<gnc, b256, 0, stream>>>(msum, Wlin + CS * C, msgb);
    k_node_h<0><<<gn, b256, 0, stream>>>(msgb, h1, sp, Wprod + C * C, Wskip + Z * C * C,
                                         Wread + C, nullptr, es, out_feats + C);

    // ---- energies ----
    k_finalize<<<gn, b256, 0, stream>>>(ne0, es, scale, shiftp, batch, out_ne, ieg);
    k_graph<<<1, G, 0, stream>>>(e0g, ieg, out_tot, out_ie);

    // ---- backward ----
    k_const1<<<1, 512, 0, stream>>>(Wread + C, Wprod + C * C, Wlin + CS * C,
                                    Wskip + Z * C * C, scale, gms1, gskip1);
    // layer 1 backward (g_msgsum is the node-independent gms1)
    k_bwd_fused<true><<<ge, b256, 0, stream>>>(pos, shifts, perm, snd_s, rcv_s, EFs, Ys,
                                               Wm1 + NB * H, w2T + H * H, w3T + CS * H,
                                               gms1, hu1, ghu1, out_F);
    // chain to layer 0
    k_gh1<<<gnc, b256, 0, stream>>>(Wread, gskip1, sp, ghu1, Wup + C * C, scale, gh1);
    k_gmsg<<<gnc, b256, 0, stream>>>(gh1, Wprod, msgb);
    k_gmsum<<<gncs, b256, 0, stream>>>(msgb, Wlin, msum);   // msum <- gm0
    // layer 0 backward
    k_bwd_fused<false><<<ge, b256, 0, stream>>>(pos, shifts, perm, snd_s, rcv_s, EFs, Ys,
                                                Wm1, w2T, w3T, msum, hu0, nullptr, out_F);

    (void)in_sizes; (void)n_in; (void)out_size; (void)ws_size; (void)eidx;
}

// Round 8
// 5484.240 us; speedup vs baseline: 2.8139x; 2.8139x over previous
//
#include <hip/hip_runtime.h>
#include <math.h>

namespace {

constexpr int N = 20000;
constexpr int E = 320000;
constexpr int EH = E / 2;          // chunk size (edges)
constexpr int C = 32;
constexpr int S = 9;
constexpr int Z = 10;
constexpr int G = 16;
constexpr int NB = 8;
constexpr int H = 64;
constexpr int CS = C * S;          // 288
constexpr float RMAX = 5.0f;
constexpr float PI_F = 3.14159265358979323846f;
constexpr float C1 = 1.7320508075688772f;   // sqrt(3)
constexpr float C2 = 3.8729833462074170f;   // sqrt(15)
constexpr float C3 = 1.1180339887498949f;   // sqrt(5)/2
constexpr float BESS_A = 0.6324555320336759f; // sqrt(2/5)

__device__ __forceinline__ float sigm(float x) { return 1.0f / (1.0f + __expf(-x)); }
__device__ __forceinline__ unsigned short f2bf(float f) {
    unsigned int u = __float_as_uint(f);
    unsigned int r = (u + 0x7FFFu + ((u >> 16) & 1u)) >> 16;
    return (unsigned short)r;
}
__device__ __forceinline__ float bf2f(unsigned short us) {
    return __uint_as_float(((unsigned int)us) << 16);
}

// ---------------- node-level kernels ----------------

__global__ void k_node_init(const float* __restrict__ attrs, const float* __restrict__ ae,
                            const float* __restrict__ Wemb, const int* __restrict__ batch,
                            int* __restrict__ sp_out, float* __restrict__ ne0,
                            float* __restrict__ h0, float* __restrict__ e0g) {
    int n = blockIdx.x * blockDim.x + threadIdx.x;
    if (n >= N) return;
    int sp = 0;
#pragma unroll
    for (int z = 0; z < Z; ++z)
        if (attrs[n * Z + z] > 0.5f) sp = z;
    sp_out[n] = sp;
    float e = ae[sp];
    ne0[n] = e;
    atomicAdd(&e0g[batch[n]], e);
#pragma unroll
    for (int c = 0; c < C; ++c) h0[n * C + c] = Wemb[sp * C + c];
}

__global__ void k_matmul_CC(const float* __restrict__ hin, const float* __restrict__ W,
                            float* __restrict__ hout) {
    int t = blockIdx.x * blockDim.x + threadIdx.x;
    if (t >= N * C) return;
    int n = t / C, d = t % C;
    float acc = 0.f;
#pragma unroll
    for (int c = 0; c < C; ++c) acc += hin[n * C + c] * W[c * C + d];
    hout[t] = acc;
}

__global__ void k_msg(const float* __restrict__ msum, const float* __restrict__ Wlin,
                      float* __restrict__ msg) {
    int t = blockIdx.x * blockDim.x + threadIdx.x;
    if (t >= N * C) return;
    int n = t / C, d = t % C;
    float acc = 0.f;
    for (int k = 0; k < CS; ++k) acc += msum[(size_t)n * CS + k] * Wlin[k * C + d];
    msg[t] = acc * (1.0f / 16.0f);
}

template <int WRITE_H>
__global__ void k_node_h(const float* __restrict__ msg, const float* __restrict__ hin,
                         const int* __restrict__ sp_arr, const float* __restrict__ Wprod,
                         const float* __restrict__ Wskip, const float* __restrict__ Wread,
                         float* __restrict__ hout_ws, float* __restrict__ es,
                         float* __restrict__ feats_out) {
    int n = blockIdx.x * blockDim.x + threadIdx.x;
    if (n >= N) return;
    int sp = sp_arr[n];
    float m[C], hi[C];
#pragma unroll
    for (int c = 0; c < C; ++c) { m[c] = msg[n * C + c]; hi[c] = hin[n * C + c]; }
    const float* Wsk = Wskip + (size_t)sp * C * C;
    float esum = 0.f;
    for (int d = 0; d < C; ++d) {
        float acc = 0.f;
#pragma unroll
        for (int c = 0; c < C; ++c) acc += m[c] * Wprod[c * C + d] + hi[c] * Wsk[c * C + d];
        esum += acc * Wread[d];
        if constexpr (WRITE_H) hout_ws[n * C + d] = acc;
        feats_out[(size_t)n * (2 * C) + d] = acc;
    }
    es[n] += esum;
}

__global__ void k_finalize(const float* __restrict__ ne0, const float* __restrict__ es,
                           const float* __restrict__ scale_p, const float* __restrict__ shift_p,
                           const int* __restrict__ batch, float* __restrict__ node_energy_out,
                           float* __restrict__ ieg) {
    int n = blockIdx.x * blockDim.x + threadIdx.x;
    if (n >= N) return;
    float nies = scale_p[0] * es[n] + shift_p[0];
    node_energy_out[n] = ne0[n] + nies;
    atomicAdd(&ieg[batch[n]], nies);
}

__global__ void k_graph(const float* __restrict__ e0g, const float* __restrict__ ieg,
                        float* __restrict__ tot_out, float* __restrict__ inter_out) {
    int g = threadIdx.x;
    if (g < G) { tot_out[g] = e0g[g] + ieg[g]; inter_out[g] = ieg[g]; }
}

__global__ void k_const1(const float* __restrict__ Wr1, const float* __restrict__ Wprod1,
                         const float* __restrict__ Wlin1, const float* __restrict__ Wskip1,
                         const float* __restrict__ scale_p, float* __restrict__ gms1,
                         float* __restrict__ gskip1) {
    int t = threadIdx.x;
    float sc = scale_p[0];
    if (t < CS) {
        float acc = 0.f;
        for (int d = 0; d < C; ++d) {
            float gm = 0.f;
#pragma unroll
            for (int d2 = 0; d2 < C; ++d2) gm += Wr1[d2] * Wprod1[d * C + d2];
            acc += gm * Wlin1[t * C + d];
        }
        gms1[t] = sc * acc * (1.0f / 16.0f);
    }
    if (t < Z * C) {
        int z = t / C, c = t % C;
        float acc = 0.f;
#pragma unroll
        for (int d = 0; d < C; ++d) acc += Wskip1[(z * C + c) * C + d] * Wr1[d];
        gskip1[t] = sc * acc;
    }
}

__global__ void k_gh1(const float* __restrict__ Wr0, const float* __restrict__ gskip1,
                      const int* __restrict__ sp_arr, const float* __restrict__ ghu1,
                      const float* __restrict__ Wup1, const float* __restrict__ scale_p,
                      float* __restrict__ gh1) {
    int t = blockIdx.x * blockDim.x + threadIdx.x;
    if (t >= N * C) return;
    int n = t / C, c = t % C;
    float acc = scale_p[0] * Wr0[c] + gskip1[sp_arr[n] * C + c];
#pragma unroll
    for (int d = 0; d < C; ++d) acc += ghu1[n * C + d] * Wup1[c * C + d];
    gh1[t] = acc;
}

__global__ void k_gmsg(const float* __restrict__ gh, const float* __restrict__ Wprod,
                       float* __restrict__ gmsg) {
    int t = blockIdx.x * blockDim.x + threadIdx.x;
    if (t >= N * C) return;
    int n = t / C, d = t % C;
    float acc = 0.f;
#pragma unroll
    for (int d2 = 0; d2 < C; ++d2) acc += gh[n * C + d2] * Wprod[d * C + d2];
    gmsg[t] = acc;
}

__global__ void k_gmsum(const float* __restrict__ gmsg, const float* __restrict__ Wlin,
                        float* __restrict__ gms) {
    int t = blockIdx.x * blockDim.x + threadIdx.x;
    if (t >= N * CS) return;
    int n = t / CS, k = t % CS;
    float acc = 0.f;
#pragma unroll
    for (int d = 0; d < C; ++d) acc += gmsg[n * C + d] * Wlin[k * C + d];
    gms[t] = acc * (1.0f / 16.0f);
}

// ---------------- CSR build (receiver-sorted) ----------------

__global__ void k_csr_count(const int* __restrict__ eidx, int* __restrict__ cnt) {
    int e = blockIdx.x * 256 + threadIdx.x;
    if (e >= E) return;
    atomicAdd(&cnt[eidx[E + e]], 1);
}

__global__ __launch_bounds__(1024) void k_csr_scan(const int* __restrict__ cnt,
                                                   int* __restrict__ rowstart,
                                                   int* __restrict__ pos) {
    __shared__ int part[1024];
    int t = threadIdx.x;
    const int CHUNK = 20;
    int base = t * CHUNK;
    int sum = 0;
    for (int i = 0; i < CHUNK; ++i) {
        int idx = base + i;
        if (idx < N) sum += cnt[idx];
    }
    part[t] = sum;
    __syncthreads();
    for (int off = 1; off < 1024; off <<= 1) {
        int v = (t >= off) ? part[t - off] : 0;
        __syncthreads();
        if (t >= off) part[t] += v;
        __syncthreads();
    }
    int run = (t == 0) ? 0 : part[t - 1];
    for (int i = 0; i < CHUNK; ++i) {
        int idx = base + i;
        if (idx < N) { rowstart[idx] = run; pos[idx] = run; run += cnt[idx]; }
    }
    if (t == 1023) rowstart[N] = run;
}

__global__ void k_csr_fill(const int* __restrict__ eidx, int* __restrict__ pos,
                           int* __restrict__ perm, int* __restrict__ snd_s,
                           int* __restrict__ rcv_s) {
    int e = blockIdx.x * 256 + threadIdx.x;
    if (e >= E) return;
    int rcv = eidx[E + e];
    int slot = atomicAdd(&pos[rcv], 1);
    perm[slot] = e;
    snd_s[slot] = eidx[e];
    rcv_s[slot] = rcv;
}

// ---------------- weight pre-transpose ----------------
__global__ void k_prep(const float* __restrict__ Wm2, const float* __restrict__ Wm3,
                       float* __restrict__ w2T, float* __restrict__ w3T) {
    int t = blockIdx.x * 256 + threadIdx.x;
    if (t < 2 * H * H) {
        int l = t / (H * H), r = t % (H * H);
        int k = r / H, j = r % H;
        w2T[t] = Wm2[l * H * H + j * H + k];
    }
    int u = t - 2 * H * H;
    if (u >= 0 && u < 2 * CS * H) {
        int l = u / (CS * H), r = u % (CS * H);
        int cs = r / H, k = r % H;
        w3T[u] = Wm3[l * H * CS + k * CS + cs];
    }
}

// ---------------- edge pipeline (receiver-sorted index i) ----------------

__global__ __launch_bounds__(256) void k_geom(
    const float* __restrict__ pos, const float* __restrict__ shifts,
    const int* __restrict__ perm, const int* __restrict__ snd_s,
    const int* __restrict__ rcv_s, float* __restrict__ Ys, float* __restrict__ EFs) {
    int i = blockIdx.x * 256 + threadIdx.x;
    int snd = snd_s[i], rcv = rcv_s[i], e = perm[i];
    float vx = pos[rcv * 3 + 0] - pos[snd * 3 + 0] + shifts[e * 3 + 0];
    float vy = pos[rcv * 3 + 1] - pos[snd * 3 + 1] + shifts[e * 3 + 1];
    float vz = pos[rcv * 3 + 2] - pos[snd * 3 + 2] + shifts[e * 3 + 2];
    float r = sqrtf(vx * vx + vy * vy + vz * vz + 1e-12f);
    float inv = 1.0f / r;
    float x = vx * inv, y = vy * inv, z = vz * inv;
    float* yr = Ys + (size_t)i * 12;
    yr[0] = 1.f;
    yr[1] = C1 * x;
    yr[2] = C1 * y;
    yr[3] = C1 * z;
    yr[4] = C2 * x * y;
    yr[5] = C2 * y * z;
    yr[6] = C3 * (3.f * z * z - 1.f);
    yr[7] = C2 * x * z;
    yr[8] = 0.5f * C2 * (x * x - y * y);
    yr[9] = 0.f; yr[10] = 0.f; yr[11] = 0.f;
    float ru = r * (1.0f / RMAX);
    float env = 0.f;
    if (ru < 1.f) {
        float u2 = ru * ru, u4 = u2 * u2, u6 = u4 * u2, u7 = u6 * ru, u8 = u7 * ru;
        env = 1.f - 28.f * u6 + 48.f * u7 - 21.f * u8;
    }
#pragma unroll
    for (int b = 0; b < NB; ++b) {
        float kb = (b + 1) * (PI_F / RMAX);
        EFs[b * E + i] = BESS_A * __sinf(kb * r) * inv * env;
    }
}

// fused radial-MLP + tpw GEMM for one edge chunk.
// MODE 0 (forward): tpw row-major [il][288] bf16 (for gather).
// MODE 1 (backward): tpw cs-plane-major [cs][il] bf16 + Z2 k-major [k][il] bf16.
template <int MODE>
__global__ __launch_bounds__(256) void k_mlp_tpw(
    const float* __restrict__ EFs, const float* __restrict__ w1g,
    const float* __restrict__ w2Tg, const float* __restrict__ w3Tg,
    int c_lo, unsigned short* __restrict__ tpw, unsigned short* __restrict__ z2out) {
    __shared__ float w1[NB * H];
    __shared__ alignas(16) float w2t[H * H];     // [k][j]
    __shared__ alignas(16) float w3t[144 * H];   // [cs_local][k]
    int tid = threadIdx.x;
    for (int idx = tid; idx < NB * H; idx += 256) w1[idx] = w1g[idx];
    {
        const float4* src = (const float4*)w2Tg;
        float4* dst = (float4*)w2t;
        for (int idx = tid; idx < H * H / 4; idx += 256) dst[idx] = src[idx];
    }
    __syncthreads();
    int il = blockIdx.x * 256 + tid;
    int i = c_lo + il;
    float ef[NB];
#pragma unroll
    for (int b = 0; b < NB; ++b) ef[b] = EFs[b * E + i];
    float t1[H];
#pragma unroll
    for (int j = 0; j < H; ++j) {
        float zz = 0.f;
#pragma unroll
        for (int b = 0; b < NB; ++b) zz += ef[b] * w1[b * H + j];
        t1[j] = zz * sigm(zz);
    }
    float t2[H];
    for (int k = 0; k < H; ++k) {
        float s0 = 0.f, s1 = 0.f, s2 = 0.f, s3 = 0.f;
#pragma unroll
        for (int jj = 0; jj < 16; ++jj) {
            float4 w = *reinterpret_cast<const float4*>(&w2t[k * H + jj * 4]);
            s0 += t1[jj * 4 + 0] * w.x;
            s1 += t1[jj * 4 + 1] * w.y;
            s2 += t1[jj * 4 + 2] * w.z;
            s3 += t1[jj * 4 + 3] * w.w;
        }
        float zz = (s0 + s1) + (s2 + s3);
        if constexpr (MODE == 1) z2out[(size_t)k * EH + il] = f2bf(zz);
        t2[k] = zz * sigm(zz);
    }
    unsigned int* orow = (unsigned int*)(tpw + (size_t)il * CS);
    for (int half = 0; half < 2; ++half) {
        __syncthreads();
        {
            const float4* src = (const float4*)(w3Tg + half * 144 * H);
            float4* dst = (float4*)w3t;
            for (int idx = tid; idx < 144 * H / 4; idx += 256) dst[idx] = src[idx];
        }
        __syncthreads();
        for (int csp = 0; csp < 72; ++csp) {
            int csl = csp * 2;
            float a0 = 0.f, a1 = 0.f;
#pragma unroll
            for (int k4 = 0; k4 < 16; ++k4) {
                float4 w0 = *reinterpret_cast<const float4*>(&w3t[csl * H + k4 * 4]);
                float4 w1v = *reinterpret_cast<const float4*>(&w3t[(csl + 1) * H + k4 * 4]);
                a0 += t2[k4 * 4 + 0] * w0.x + t2[k4 * 4 + 1] * w0.y
                    + t2[k4 * 4 + 2] * w0.z + t2[k4 * 4 + 3] * w0.w;
                a1 += t2[k4 * 4 + 0] * w1v.x + t2[k4 * 4 + 1] * w1v.y
                    + t2[k4 * 4 + 2] * w1v.z + t2[k4 * 4 + 3] * w1v.w;
            }
            if constexpr (MODE == 0) {
                orow[half * 72 + csp] =
                    (unsigned int)f2bf(a0) | ((unsigned int)f2bf(a1) << 16);
            } else {
                int cs = half * 144 + csl;
                tpw[(size_t)cs * EH + il] = f2bf(a0);
                tpw[(size_t)(cs + 1) * EH + il] = f2bf(a1);
            }
        }
    }
}

// gather: wave per node, lane = cs-slot; contiguous sorted edges (row-major tpw).
__global__ __launch_bounds__(512) void k_gather(
    const int* __restrict__ rowstart, const int* __restrict__ snd_s,
    const float* __restrict__ hu, const unsigned short* __restrict__ tpw,
    const float* __restrict__ Ys, float* __restrict__ msum,
    int c_lo, int c_hi) {
    int tid = threadIdx.x;
    int wave = tid >> 6, lane = tid & 63;
    int n = blockIdx.x * 8 + wave;
    int i0 = rowstart[n], i1 = rowstart[n + 1];
    if (i0 < c_lo) i0 = c_lo;
    if (i1 > c_hi) i1 = c_hi;
    if (i0 >= i1) return;
    bool has4 = lane < 32;
    int cs4m = has4 ? lane + 256 : lane;
    const int ci0 = lane / 9,         si0 = lane % 9;
    const int ci1 = (lane + 64) / 9,  si1 = (lane + 64) % 9;
    const int ci2 = (lane + 128) / 9, si2 = (lane + 128) % 9;
    const int ci3 = (lane + 192) / 9, si3 = (lane + 192) % 9;
    const int ci4 = cs4m / 9,         si4 = cs4m % 9;
    float acc0 = 0.f, acc1 = 0.f, acc2 = 0.f, acc3 = 0.f, acc4 = 0.f;
    for (int i = i0; i < i1; ++i) {
        int snd = snd_s[i];
        const unsigned short* tr = tpw + (size_t)(i - c_lo) * CS;
        float t0 = bf2f(tr[lane]);
        float t1v = bf2f(tr[lane + 64]);
        float t2v = bf2f(tr[lane + 128]);
        float t3v = bf2f(tr[lane + 192]);
        float t4v = bf2f(tr[cs4m]);
        const float* yr = Ys + (size_t)i * 12;
        float y0 = yr[si0], y1 = yr[si1], y2 = yr[si2], y3 = yr[si3], y4 = yr[si4];
        const float* hr = hu + (size_t)snd * C;
        float h0 = hr[ci0], h1 = hr[ci1], h2 = hr[ci2], h3 = hr[ci3], h4 = hr[ci4];
        acc0 += h0 * y0 * t0;
        acc1 += h1 * y1 * t1v;
        acc2 += h2 * y2 * t2v;
        acc3 += h3 * y3 * t3v;
        acc4 += h4 * y4 * t4v;
    }
    float* mrow = msum + (size_t)n * CS;
    mrow[lane] += acc0;
    mrow[lane + 64] += acc1;
    mrow[lane + 128] += acc2;
    mrow[lane + 192] += acc3;
    if (has4) mrow[lane + 256] += acc4;
}

// backward stage A: per edge, stream cs once (plane-major tpw, coalesced):
// gY[s] += gm*hu*tpw; ghu[snd,c] += gm*Y*tpw (L1); gt2[k] += (gm*hu*Y)*W3[k,cs].
template <bool L1>
__global__ __launch_bounds__(256) void k_bwd12(
    const int* __restrict__ snd_s, const int* __restrict__ rcv_s,
    const unsigned short* __restrict__ tpw, const float* __restrict__ Ys,
    const float* __restrict__ gm, const float* __restrict__ hu,
    const float* __restrict__ w3Tg, float* __restrict__ ghu,
    float* __restrict__ GYc, float* __restrict__ GT2c, int c_lo) {
    __shared__ alignas(16) float w3t[144 * H];   // [cs_local][k]
    int tid = threadIdx.x;
    int il = blockIdx.x * 256 + tid;
    int i = c_lo + il;
    int snd = snd_s[i], rcv = rcv_s[i];
    float ysr[S];
#pragma unroll
    for (int s = 0; s < S; ++s) ysr[s] = Ys[(size_t)i * 12 + s];
    float gY[S];
#pragma unroll
    for (int s = 0; s < S; ++s) gY[s] = 0.f;
    float gt2[H];
#pragma unroll
    for (int k = 0; k < H; ++k) gt2[k] = 0.f;
    const float* gmrow = L1 ? gm : (gm + (size_t)rcv * CS);
    for (int half = 0; half < 2; ++half) {
        __syncthreads();
        {
            const float4* src = (const float4*)(w3Tg + half * 144 * H);
            float4* dst = (float4*)w3t;
            for (int idx = tid; idx < 144 * H / 4; idx += 256) dst[idx] = src[idx];
        }
        __syncthreads();
        for (int cc = 0; cc < 16; ++cc) {
            int c = half * 16 + cc;
            float hv = hu[(size_t)snd * C + c];
            float ghc = 0.f;
#pragma unroll
            for (int s = 0; s < S; ++s) {
                int csl = cc * 9 + s;
                int cs = c * 9 + s;
                float gmv = gmrow[cs];
                float yv = ysr[s];
                float tpwv = bf2f(tpw[(size_t)cs * EH + il]);
                float p = gmv * hv;
                gY[s] += p * tpwv;
                ghc += gmv * yv * tpwv;
                float gtw = p * yv;
#pragma unroll
                for (int k4 = 0; k4 < 16; ++k4) {
                    float4 w = *reinterpret_cast<const float4*>(&w3t[csl * H + k4 * 4]);
                    gt2[k4 * 4 + 0] += gtw * w.x;
                    gt2[k4 * 4 + 1] += gtw * w.y;
                    gt2[k4 * 4 + 2] += gtw * w.z;
                    gt2[k4 * 4 + 3] += gtw * w.w;
                }
            }
            if constexpr (L1) atomicAdd(&ghu[(size_t)snd * C + c], ghc);
        }
    }
#pragma unroll
    for (int s = 0; s < S; ++s) GYc[(size_t)il * 12 + s] = gY[s];
#pragma unroll
    for (int k = 0; k < H; ++k) GT2c[(size_t)k * EH + il] = gt2[k];   // coalesced per k
}

// backward stage B: streaming MLP backward (via stored Z2) + geometry + force atomics
__global__ __launch_bounds__(256) void k_mlp_bwd_c(
    const float* __restrict__ pos, const float* __restrict__ shifts,
    const int* __restrict__ perm, const int* __restrict__ snd_s,
    const int* __restrict__ rcv_s, const float* __restrict__ EFs,
    const unsigned short* __restrict__ Z2c, const float* __restrict__ GT2c,
    const float* __restrict__ GYc, const float* __restrict__ w1g,
    const float* __restrict__ w2Tg, float* __restrict__ forces, int c_lo) {
    __shared__ float w1[NB * H];
    __shared__ alignas(16) float w2t[H * H];   // [k][j]
    int tid = threadIdx.x;
    for (int idx = tid; idx < NB * H; idx += 256) w1[idx] = w1g[idx];
    {
        const float4* src = (const float4*)w2Tg;
        float4* dst = (float4*)w2t;
        for (int idx = tid; idx < H * H / 4; idx += 256) dst[idx] = src[idx];
    }
    __syncthreads();
    int il = blockIdx.x * 256 + tid;
    int i = c_lo + il;
    int snd = snd_s[i], rcv = rcv_s[i];

    float gt1[H];
#pragma unroll
    for (int j = 0; j < H; ++j) gt1[j] = 0.f;
    for (int k = 0; k < H; ++k) {
        float zz = bf2f(Z2c[(size_t)k * EH + il]);
        float g = GT2c[(size_t)k * EH + il];
        float sg = sigm(zz);
        float gz2 = g * sg * (1.f + zz * (1.f - sg));
#pragma unroll
        for (int jj = 0; jj < 16; ++jj) {
            float4 w = *reinterpret_cast<const float4*>(&w2t[k * H + jj * 4]);
            gt1[jj * 4 + 0] += gz2 * w.x;
            gt1[jj * 4 + 1] += gz2 * w.y;
            gt1[jj * 4 + 2] += gz2 * w.z;
            gt1[jj * 4 + 3] += gz2 * w.w;
        }
    }
    float ef[NB];
#pragma unroll
    for (int b = 0; b < NB; ++b) ef[b] = EFs[b * E + i];
    float gef[NB];
#pragma unroll
    for (int b = 0; b < NB; ++b) gef[b] = 0.f;
#pragma unroll
    for (int j = 0; j < H; ++j) {
        float z1 = 0.f;
#pragma unroll
        for (int b = 0; b < NB; ++b) z1 += ef[b] * w1[b * H + j];
        float sg = sigm(z1);
        float gz1 = gt1[j] * sg * (1.f + z1 * (1.f - sg));
#pragma unroll
        for (int b = 0; b < NB; ++b) gef[b] += gz1 * w1[b * H + j];
    }
    int e = perm[i];
    float vx = pos[rcv * 3 + 0] - pos[snd * 3 + 0] + shifts[e * 3 + 0];
    float vy = pos[rcv * 3 + 1] - pos[snd * 3 + 1] + shifts[e * 3 + 1];
    float vz = pos[rcv * 3 + 2] - pos[snd * 3 + 2] + shifts[e * 3 + 2];
    float r = sqrtf(vx * vx + vy * vy + vz * vz + 1e-12f);
    float inv = 1.0f / r;
    float x = vx * inv, y = vy * inv, z = vz * inv;
    float ru = r * (1.0f / RMAX);
    float env = 0.f, denv_dr = 0.f;
    if (ru < 1.f) {
        float u2 = ru * ru, u4 = u2 * u2, u5 = u4 * ru, u6 = u5 * ru, u7 = u6 * ru, u8 = u7 * ru;
        env = 1.f - 28.f * u6 + 48.f * u7 - 21.f * u8;
        denv_dr = (-168.f * u5 + 336.f * u6 - 168.f * u7) * (1.0f / RMAX);
    }
    float gr = 0.f;
#pragma unroll
    for (int b = 0; b < NB; ++b) {
        float kb = (b + 1) * (PI_F / RMAX);
        float sb = __sinf(kb * r), cb = __cosf(kb * r);
        float bess = BESS_A * sb * inv;
        float dbess = BESS_A * (kb * cb - sb * inv) * inv;
        gr += gef[b] * (dbess * env + bess * denv_dr);
    }
    float gys[S];
#pragma unroll
    for (int s = 0; s < S; ++s) gys[s] = GYc[(size_t)il * 12 + s];
    float gx = C1 * gys[1] + C2 * y * gys[4] + C2 * z * gys[7] + C2 * x * gys[8];
    float gy = C1 * gys[2] + C2 * x * gys[4] + C2 * z * gys[5] - C2 * y * gys[8];
    float gz = C1 * gys[3] + C2 * y * gys[5] + 6.f * C3 * z * gys[6] + C2 * x * gys[7];
    float dot = gx * x + gy * y + gz * z;
    float gvx = (gx - dot * x) * inv + gr * x;
    float gvy = (gy - dot * y) * inv + gr * y;
    float gvz = (gz - dot * z) * inv + gr * z;
    atomicAdd(&forces[snd * 3 + 0], gvx);
    atomicAdd(&forces[snd * 3 + 1], gvy);
    atomicAdd(&forces[snd * 3 + 2], gvz);
    atomicAdd(&forces[rcv * 3 + 0], -gvx);
    atomicAdd(&forces[rcv * 3 + 1], -gvy);
    atomicAdd(&forces[rcv * 3 + 2], -gvz);
}

} // namespace

extern "C" void kernel_launch(void* const* d_in, const int* in_sizes, int n_in,
                              void* d_out, int out_size, void* d_ws, size_t ws_size,
                              hipStream_t stream) {
    const float* pos    = (const float*)d_in[0];
    const float* attrs  = (const float*)d_in[1];
    const float* shifts = (const float*)d_in[2];
    const float* ae     = (const float*)d_in[3];
    const float* Wemb   = (const float*)d_in[4];
    const float* Wup    = (const float*)d_in[5];
    const float* Wm1    = (const float*)d_in[6];
    const float* Wm2    = (const float*)d_in[7];
    const float* Wm3    = (const float*)d_in[8];
    const float* Wlin   = (const float*)d_in[9];
    const float* Wskip  = (const float*)d_in[10];
    const float* Wprod  = (const float*)d_in[11];
    const float* Wread  = (const float*)d_in[12];
    const float* scale  = (const float*)d_in[13];
    const float* shiftp = (const float*)d_in[14];
    const int*   eidx   = (const int*)d_in[15];
    const int*   batch  = (const int*)d_in[16];

    float* out       = (float*)d_out;
    float* out_tot   = out;                     // G
    float* out_ne    = out + G;                 // N
    float* out_ie    = out + G + N;             // G
    float* out_F     = out + 2 * G + N;         // N*3
    float* out_feats = out + 2 * G + N + 3 * N; // N*2C

    char* w = (char*)d_ws;
    auto alloc = [&](size_t bytes) { void* p = (void*)w; w += (bytes + 255) & ~(size_t)255; return p; };
    int*   sp     = (int*)alloc((size_t)N * 4);
    float* ne0    = (float*)alloc((size_t)N * 4);
    float* es     = (float*)alloc((size_t)N * 4);
    float* e0g    = (float*)alloc((size_t)G * 4);
    float* ieg    = (float*)alloc((size_t)G * 4);
    float* h0     = (float*)alloc((size_t)N * C * 4);
    float* h1     = (float*)alloc((size_t)N * C * 4);
    float* hu0    = (float*)alloc((size_t)N * C * 4);
    float* hu1    = (float*)alloc((size_t)N * C * 4);
    float* msgb   = (float*)alloc((size_t)N * C * 4);
    float* ghu1   = (float*)alloc((size_t)N * C * 4);
    float* gh1    = (float*)alloc((size_t)N * C * 4);
    float* gms1   = (float*)alloc((size_t)CS * 4);
    float* gskip1 = (float*)alloc((size_t)Z * C * 4);
    int*   cnt    = (int*)alloc((size_t)N * 4);
    int*   rowst  = (int*)alloc((size_t)(N + 1) * 4);
    int*   posb   = (int*)alloc((size_t)N * 4);
    int*   perm   = (int*)alloc((size_t)E * 4);
    int*   snd_s  = (int*)alloc((size_t)E * 4);
    int*   rcv_s  = (int*)alloc((size_t)E * 4);
    float* msum   = (float*)alloc((size_t)N * CS * 4);     // fwd msgsum / bwd gm0
    float* EFs    = (float*)alloc((size_t)NB * E * 4);
    float* Ys     = (float*)alloc((size_t)E * 12 * 4);
    float* w2T    = (float*)alloc((size_t)2 * H * H * 4);
    float* w3T    = (float*)alloc((size_t)2 * CS * H * 4);
    unsigned short* tpw = (unsigned short*)alloc((size_t)EH * CS * 2);   // 92.2 MB
    unsigned short* Z2c = (unsigned short*)alloc((size_t)EH * H * 2);    // 20.5 MB
    float* GT2c  = (float*)alloc((size_t)EH * H * 4);                    // 41.0 MB
    float* GYc   = (float*)alloc((size_t)EH * 12 * 4);                   // 7.7 MB

    hipMemsetAsync(es, 0, (size_t)N * 4, stream);
    hipMemsetAsync(e0g, 0, (size_t)G * 4, stream);
    hipMemsetAsync(ieg, 0, (size_t)G * 4, stream);
    hipMemsetAsync(ghu1, 0, (size_t)N * C * 4, stream);
    hipMemsetAsync(cnt, 0, (size_t)N * 4, stream);
    hipMemsetAsync(out_F, 0, (size_t)N * 3 * 4, stream);

    dim3 b256(256);
    int gn   = (N + 255) / 256;
    int gnc  = (N * C + 255) / 256;
    int gncs = (N * CS + 255) / 256;
    int ge   = E / 256;                 // 1250, exact
    int geh  = EH / 256;                // 625, exact
    int gg   = N / 8;                   // 2500, exact

    // CSR build (receiver-sorted)
    k_csr_count<<<ge, b256, 0, stream>>>(eidx, cnt);
    k_csr_scan<<<1, 1024, 0, stream>>>(cnt, rowst, posb);
    k_csr_fill<<<ge, b256, 0, stream>>>(eidx, posb, perm, snd_s, rcv_s);

    k_node_init<<<gn, b256, 0, stream>>>(attrs, ae, Wemb, batch, sp, ne0, h0, e0g);
    k_prep<<<176, b256, 0, stream>>>(Wm2, Wm3, w2T, w3T);
    k_geom<<<ge, b256, 0, stream>>>(pos, shifts, perm, snd_s, rcv_s, Ys, EFs);

    // ---- layer 0 forward ----
    k_matmul_CC<<<gnc, b256, 0, stream>>>(h0, Wup, hu0);
    hipMemsetAsync(msum, 0, (size_t)N * CS * 4, stream);
    for (int cchunk = 0; cchunk < 2; ++cchunk) {
        int lo = cchunk * EH, hi = lo + EH;
        k_mlp_tpw<0><<<geh, b256, 0, stream>>>(EFs, Wm1, w2T, w3T, lo, tpw, nullptr);
        k_gather<<<gg, 512, 0, stream>>>(rowst, snd_s, hu0, tpw, Ys, msum, lo, hi);
    }
    k_msg<<<gnc, b256, 0, stream>>>(msum, Wlin, msgb);
    k_node_h<1><<<gn, b256, 0, stream>>>(msgb, h0, sp, Wprod, Wskip, Wread, h1, es, out_feats);

    // ---- layer 1 forward ----
    k_matmul_CC<<<gnc, b256, 0, stream>>>(h1, Wup + C * C, hu1);
    hipMemsetAsync(msum, 0, (size_t)N * CS * 4, stream);
    for (int cchunk = 0; cchunk < 2; ++cchunk) {
        int lo = cchunk * EH, hi = lo + EH;
        k_mlp_tpw<0><<<geh, b256, 0, stream>>>(EFs, Wm1 + NB * H, w2T + H * H, w3T + CS * H,
                                               lo, tpw, nullptr);
        k_gather<<<gg, 512, 0, stream>>>(rowst, snd_s, hu1, tpw, Ys, msum, lo, hi);
    }
    k_msg<<<gnc, b256, 0, stream>>>(msum, Wlin + CS * C, msgb);
    k_node_h<0><<<gn, b256, 0, stream>>>(msgb, h1, sp, Wprod + C * C, Wskip + Z * C * C,
                                         Wread + C, nullptr, es, out_feats + C);

    // ---- energies ----
    k_finalize<<<gn, b256, 0, stream>>>(ne0, es, scale, shiftp, batch, out_ne, ieg);
    k_graph<<<1, G, 0, stream>>>(e0g, ieg, out_tot, out_ie);

    // ---- backward ----
    k_const1<<<1, 512, 0, stream>>>(Wread + C, Wprod + C * C, Wlin + CS * C,
                                    Wskip + Z * C * C, scale, gms1, gskip1);
    // layer 1 backward (gm = node-independent gms1), chunked
    for (int cchunk = 0; cchunk < 2; ++cchunk) {
        int lo = cchunk * EH;
        k_mlp_tpw<1><<<geh, b256, 0, stream>>>(EFs, Wm1 + NB * H, w2T + H * H,
                                               w3T + CS * H, lo, tpw, Z2c);
        k_bwd12<true><<<geh, b256, 0, stream>>>(snd_s, rcv_s, tpw, Ys, gms1, hu1,
                                                w3T + CS * H, ghu1, GYc, GT2c, lo);
        k_mlp_bwd_c<<<geh, b256, 0, stream>>>(pos, shifts, perm, snd_s, rcv_s, EFs, Z2c,
                                              GT2c, GYc, Wm1 + NB * H, w2T + H * H,
                                              out_F, lo);
    }
    // chain to layer 0
    k_gh1<<<gnc, b256, 0, stream>>>(Wread, gskip1, sp, ghu1, Wup + C * C, scale, gh1);
    k_gmsg<<<gnc, b256, 0, stream>>>(gh1, Wprod, msgb);
    k_gmsum<<<gncs, b256, 0, stream>>>(msgb, Wlin, msum);   // msum <- gm0
    // layer 0 backward, chunked
    for (int cchunk = 0; cchunk < 2; ++cchunk) {
        int lo = cchunk * EH;
        k_mlp_tpw<1><<<geh, b256, 0, stream>>>(EFs, Wm1, w2T, w3T, lo, tpw, Z2c);
        k_bwd12<false><<<geh, b256, 0, stream>>>(snd_s, rcv_s, tpw, Ys, msum, hu0,
                                                 w3T, nullptr, GYc, GT2c, lo);
        k_mlp_bwd_c<<<geh, b256, 0, stream>>>(pos, shifts, perm, snd_s, rcv_s, EFs, Z2c,
                                              GT2c, GYc, Wm1, w2T, out_F, lo);
    }

    (void)in_sizes; (void)n_in; (void)out_size; (void)ws_size; (void)eidx;
}

// Round 9
// 4195.850 us; speedup vs baseline: 3.6780x; 1.3071x over previous
//
#include <hip/hip_runtime.h>
#include <math.h>

namespace {

constexpr int N = 20000;
constexpr int E = 320000;
constexpr int EH = E / 2;          // chunk size (edges)
constexpr int C = 32;
constexpr int S = 9;
constexpr int Z = 10;
constexpr int G = 16;
constexpr int NB = 8;
constexpr int H = 64;
constexpr int CS = C * S;          // 288
constexpr float RMAX = 5.0f;
constexpr float PI_F = 3.14159265358979323846f;
constexpr float C1 = 1.7320508075688772f;   // sqrt(3)
constexpr float C2 = 3.8729833462074170f;   // sqrt(15)
constexpr float C3 = 1.1180339887498949f;   // sqrt(5)/2
constexpr float BESS_A = 0.6324555320336759f; // sqrt(2/5)

__device__ __forceinline__ float sigm(float x) { return 1.0f / (1.0f + __expf(-x)); }
__device__ __forceinline__ unsigned short f2bf(float f) {
    unsigned int u = __float_as_uint(f);
    unsigned int r = (u + 0x7FFFu + ((u >> 16) & 1u)) >> 16;
    return (unsigned short)r;
}
__device__ __forceinline__ float bf2f(unsigned short us) {
    return __uint_as_float(((unsigned int)us) << 16);
}

// ---------------- node-level kernels ----------------

__global__ void k_node_init(const float* __restrict__ attrs, const float* __restrict__ ae,
                            const float* __restrict__ Wemb, const int* __restrict__ batch,
                            int* __restrict__ sp_out, float* __restrict__ ne0,
                            float* __restrict__ h0, float* __restrict__ e0g) {
    int n = blockIdx.x * blockDim.x + threadIdx.x;
    if (n >= N) return;
    int sp = 0;
#pragma unroll
    for (int z = 0; z < Z; ++z)
        if (attrs[n * Z + z] > 0.5f) sp = z;
    sp_out[n] = sp;
    float e = ae[sp];
    ne0[n] = e;
    atomicAdd(&e0g[batch[n]], e);
#pragma unroll
    for (int c = 0; c < C; ++c) h0[n * C + c] = Wemb[sp * C + c];
}

__global__ void k_matmul_CC(const float* __restrict__ hin, const float* __restrict__ W,
                            float* __restrict__ hout) {
    int t = blockIdx.x * blockDim.x + threadIdx.x;
    if (t >= N * C) return;
    int n = t / C, d = t % C;
    float acc = 0.f;
#pragma unroll
    for (int c = 0; c < C; ++c) acc += hin[n * C + c] * W[c * C + d];
    hout[t] = acc;
}

__global__ void k_msg(const float* __restrict__ msum, const float* __restrict__ Wlin,
                      float* __restrict__ msg) {
    int t = blockIdx.x * blockDim.x + threadIdx.x;
    if (t >= N * C) return;
    int n = t / C, d = t % C;
    float acc = 0.f;
    for (int k = 0; k < CS; ++k) acc += msum[(size_t)n * CS + k] * Wlin[k * C + d];
    msg[t] = acc * (1.0f / 16.0f);
}

template <int WRITE_H>
__global__ void k_node_h(const float* __restrict__ msg, const float* __restrict__ hin,
                         const int* __restrict__ sp_arr, const float* __restrict__ Wprod,
                         const float* __restrict__ Wskip, const float* __restrict__ Wread,
                         float* __restrict__ hout_ws, float* __restrict__ es,
                         float* __restrict__ feats_out) {
    int n = blockIdx.x * blockDim.x + threadIdx.x;
    if (n >= N) return;
    int sp = sp_arr[n];
    float m[C], hi[C];
#pragma unroll
    for (int c = 0; c < C; ++c) { m[c] = msg[n * C + c]; hi[c] = hin[n * C + c]; }
    const float* Wsk = Wskip + (size_t)sp * C * C;
    float esum = 0.f;
    for (int d = 0; d < C; ++d) {
        float acc = 0.f;
#pragma unroll
        for (int c = 0; c < C; ++c) acc += m[c] * Wprod[c * C + d] + hi[c] * Wsk[c * C + d];
        esum += acc * Wread[d];
        if constexpr (WRITE_H) hout_ws[n * C + d] = acc;
        feats_out[(size_t)n * (2 * C) + d] = acc;
    }
    es[n] += esum;
}

__global__ void k_finalize(const float* __restrict__ ne0, const float* __restrict__ es,
                           const float* __restrict__ scale_p, const float* __restrict__ shift_p,
                           const int* __restrict__ batch, float* __restrict__ node_energy_out,
                           float* __restrict__ ieg) {
    int n = blockIdx.x * blockDim.x + threadIdx.x;
    if (n >= N) return;
    float nies = scale_p[0] * es[n] + shift_p[0];
    node_energy_out[n] = ne0[n] + nies;
    atomicAdd(&ieg[batch[n]], nies);
}

__global__ void k_graph(const float* __restrict__ e0g, const float* __restrict__ ieg,
                        float* __restrict__ tot_out, float* __restrict__ inter_out) {
    int g = threadIdx.x;
    if (g < G) { tot_out[g] = e0g[g] + ieg[g]; inter_out[g] = ieg[g]; }
}

__global__ void k_const1(const float* __restrict__ Wr1, const float* __restrict__ Wprod1,
                         const float* __restrict__ Wlin1, const float* __restrict__ Wskip1,
                         const float* __restrict__ scale_p, float* __restrict__ gms1,
                         float* __restrict__ gskip1) {
    int t = threadIdx.x;
    float sc = scale_p[0];
    if (t < CS) {
        float acc = 0.f;
        for (int d = 0; d < C; ++d) {
            float gm = 0.f;
#pragma unroll
            for (int d2 = 0; d2 < C; ++d2) gm += Wr1[d2] * Wprod1[d * C + d2];
            acc += gm * Wlin1[t * C + d];
        }
        gms1[t] = sc * acc * (1.0f / 16.0f);
    }
    if (t < Z * C) {
        int z = t / C, c = t % C;
        float acc = 0.f;
#pragma unroll
        for (int d = 0; d < C; ++d) acc += Wskip1[(z * C + c) * C + d] * Wr1[d];
        gskip1[t] = sc * acc;
    }
}

__global__ void k_gh1(const float* __restrict__ Wr0, const float* __restrict__ gskip1,
                      const int* __restrict__ sp_arr, const float* __restrict__ ghu1,
                      const float* __restrict__ Wup1, const float* __restrict__ scale_p,
                      float* __restrict__ gh1) {
    int t = blockIdx.x * blockDim.x + threadIdx.x;
    if (t >= N * C) return;
    int n = t / C, c = t % C;
    float acc = scale_p[0] * Wr0[c] + gskip1[sp_arr[n] * C + c];
#pragma unroll
    for (int d = 0; d < C; ++d) acc += ghu1[n * C + d] * Wup1[c * C + d];
    gh1[t] = acc;
}

__global__ void k_gmsg(const float* __restrict__ gh, const float* __restrict__ Wprod,
                       float* __restrict__ gmsg) {
    int t = blockIdx.x * blockDim.x + threadIdx.x;
    if (t >= N * C) return;
    int n = t / C, d = t % C;
    float acc = 0.f;
#pragma unroll
    for (int d2 = 0; d2 < C; ++d2) acc += gh[n * C + d2] * Wprod[d * C + d2];
    gmsg[t] = acc;
}

__global__ void k_gmsum(const float* __restrict__ gmsg, const float* __restrict__ Wlin,
                        float* __restrict__ gms) {
    int t = blockIdx.x * blockDim.x + threadIdx.x;
    if (t >= N * CS) return;
    int n = t / CS, k = t % CS;
    float acc = 0.f;
#pragma unroll
    for (int d = 0; d < C; ++d) acc += gmsg[n * C + d] * Wlin[k * C + d];
    gms[t] = acc * (1.0f / 16.0f);
}

// ---------------- CSR build (receiver-sorted) ----------------

__global__ void k_csr_count(const int* __restrict__ eidx, int* __restrict__ cnt) {
    int e = blockIdx.x * 256 + threadIdx.x;
    if (e >= E) return;
    atomicAdd(&cnt[eidx[E + e]], 1);
}

__global__ __launch_bounds__(1024) void k_csr_scan(const int* __restrict__ cnt,
                                                   int* __restrict__ rowstart,
                                                   int* __restrict__ pos) {
    __shared__ int part[1024];
    int t = threadIdx.x;
    const int CHUNK = 20;
    int base = t * CHUNK;
    int sum = 0;
    for (int i = 0; i < CHUNK; ++i) {
        int idx = base + i;
        if (idx < N) sum += cnt[idx];
    }
    part[t] = sum;
    __syncthreads();
    for (int off = 1; off < 1024; off <<= 1) {
        int v = (t >= off) ? part[t - off] : 0;
        __syncthreads();
        if (t >= off) part[t] += v;
        __syncthreads();
    }
    int run = (t == 0) ? 0 : part[t - 1];
    for (int i = 0; i < CHUNK; ++i) {
        int idx = base + i;
        if (idx < N) { rowstart[idx] = run; pos[idx] = run; run += cnt[idx]; }
    }
    if (t == 1023) rowstart[N] = run;
}

__global__ void k_csr_fill(const int* __restrict__ eidx, int* __restrict__ pos,
                           int* __restrict__ perm, int* __restrict__ snd_s,
                           int* __restrict__ rcv_s) {
    int e = blockIdx.x * 256 + threadIdx.x;
    if (e >= E) return;
    int rcv = eidx[E + e];
    int slot = atomicAdd(&pos[rcv], 1);
    perm[slot] = e;
    snd_s[slot] = eidx[e];
    rcv_s[slot] = rcv;
}

// ---------------- weight pre-transpose ----------------
// w2T[l][k*H+j] = Wm2[l][j*H+k];  w3T[l][cs*H+k] = Wm3[l][k*CS+cs]
__global__ void k_prep(const float* __restrict__ Wm2, const float* __restrict__ Wm3,
                       float* __restrict__ w2T, float* __restrict__ w3T) {
    int t = blockIdx.x * 256 + threadIdx.x;
    if (t < 2 * H * H) {
        int l = t / (H * H), r = t % (H * H);
        int k = r / H, j = r % H;
        w2T[t] = Wm2[l * H * H + j * H + k];
    }
    int u = t - 2 * H * H;
    if (u >= 0 && u < 2 * CS * H) {
        int l = u / (CS * H), r = u % (CS * H);
        int cs = r / H, k = r % H;
        w3T[u] = Wm3[l * H * CS + k * CS + cs];
    }
}

// ---------------- edge pipeline (receiver-sorted index i) ----------------

__global__ __launch_bounds__(256) void k_geom(
    const float* __restrict__ pos, const float* __restrict__ shifts,
    const int* __restrict__ perm, const int* __restrict__ snd_s,
    const int* __restrict__ rcv_s, float* __restrict__ Ys, float* __restrict__ EFs) {
    int i = blockIdx.x * 256 + threadIdx.x;
    int snd = snd_s[i], rcv = rcv_s[i], e = perm[i];
    float vx = pos[rcv * 3 + 0] - pos[snd * 3 + 0] + shifts[e * 3 + 0];
    float vy = pos[rcv * 3 + 1] - pos[snd * 3 + 1] + shifts[e * 3 + 1];
    float vz = pos[rcv * 3 + 2] - pos[snd * 3 + 2] + shifts[e * 3 + 2];
    float r = sqrtf(vx * vx + vy * vy + vz * vz + 1e-12f);
    float inv = 1.0f / r;
    float x = vx * inv, y = vy * inv, z = vz * inv;
    float* yr = Ys + (size_t)i * 12;
    yr[0] = 1.f;
    yr[1] = C1 * x;
    yr[2] = C1 * y;
    yr[3] = C1 * z;
    yr[4] = C2 * x * y;
    yr[5] = C2 * y * z;
    yr[6] = C3 * (3.f * z * z - 1.f);
    yr[7] = C2 * x * z;
    yr[8] = 0.5f * C2 * (x * x - y * y);
    yr[9] = 0.f; yr[10] = 0.f; yr[11] = 0.f;
    float ru = r * (1.0f / RMAX);
    float env = 0.f;
    if (ru < 1.f) {
        float u2 = ru * ru, u4 = u2 * u2, u6 = u4 * u2, u7 = u6 * ru, u8 = u7 * ru;
        env = 1.f - 28.f * u6 + 48.f * u7 - 21.f * u8;
    }
#pragma unroll
    for (int b = 0; b < NB; ++b) {
        float kb = (b + 1) * (PI_F / RMAX);
        EFs[b * E + i] = BESS_A * __sinf(kb * r) * inv * env;
    }
}

// fused radial-MLP + tpw GEMM for one edge chunk.
// Writes row-major tpw [il][288] bf16 and Z2 k-major [k][il] bf16.
// Weights read straight from global with wave-uniform indices (scalarizable).
__global__ __launch_bounds__(256) void k_mlp_tpw(
    const float* __restrict__ EFs, const float* __restrict__ w1g,
    const float* __restrict__ w2Tg, const float* __restrict__ w3Tg,
    int c_lo, unsigned short* __restrict__ tpw, unsigned short* __restrict__ z2out) {
    int tid = threadIdx.x;
    int il = blockIdx.x * 256 + tid;
    int i = c_lo + il;
    float ef[NB];
#pragma unroll
    for (int b = 0; b < NB; ++b) ef[b] = EFs[b * E + i];
    float t1[H];
#pragma unroll
    for (int j = 0; j < H; ++j) {
        float zz = 0.f;
#pragma unroll
        for (int b = 0; b < NB; ++b) zz += ef[b] * w1g[b * H + j];
        t1[j] = zz * sigm(zz);
    }
    const float4* w2q = (const float4*)w2Tg;   // [k][j] rows of 16 float4
    float t2[H];
    for (int k = 0; k < H; ++k) {
        float s0 = 0.f, s1 = 0.f, s2 = 0.f, s3 = 0.f;
#pragma unroll
        for (int jj = 0; jj < 16; ++jj) {
            float4 w = w2q[k * 16 + jj];
            s0 += t1[jj * 4 + 0] * w.x;
            s1 += t1[jj * 4 + 1] * w.y;
            s2 += t1[jj * 4 + 2] * w.z;
            s3 += t1[jj * 4 + 3] * w.w;
        }
        float zz = (s0 + s1) + (s2 + s3);
        z2out[(size_t)k * EH + il] = f2bf(zz);
        t2[k] = zz * sigm(zz);
    }
    const float4* w3q = (const float4*)w3Tg;   // [cs][k] rows of 16 float4
    unsigned int* orow = (unsigned int*)(tpw + (size_t)il * CS);
    for (int csp = 0; csp < 144; ++csp) {
        int csl = csp * 2;
        float a0 = 0.f, a1 = 0.f;
#pragma unroll
        for (int k4 = 0; k4 < 16; ++k4) {
            float4 w0 = w3q[csl * 16 + k4];
            float4 w1v = w3q[(csl + 1) * 16 + k4];
            a0 += t2[k4 * 4 + 0] * w0.x + t2[k4 * 4 + 1] * w0.y
                + t2[k4 * 4 + 2] * w0.z + t2[k4 * 4 + 3] * w0.w;
            a1 += t2[k4 * 4 + 0] * w1v.x + t2[k4 * 4 + 1] * w1v.y
                + t2[k4 * 4 + 2] * w1v.z + t2[k4 * 4 + 3] * w1v.w;
        }
        orow[csp] = (unsigned int)f2bf(a0) | ((unsigned int)f2bf(a1) << 16);
    }
}

// gather: wave per node, lane = cs-slot; contiguous sorted edges (row-major tpw).
__global__ __launch_bounds__(512) void k_gather(
    const int* __restrict__ rowstart, const int* __restrict__ snd_s,
    const float* __restrict__ hu, const unsigned short* __restrict__ tpw,
    const float* __restrict__ Ys, float* __restrict__ msum,
    int c_lo, int c_hi) {
    int tid = threadIdx.x;
    int wave = tid >> 6, lane = tid & 63;
    int n = blockIdx.x * 8 + wave;
    int i0 = rowstart[n], i1 = rowstart[n + 1];
    if (i0 < c_lo) i0 = c_lo;
    if (i1 > c_hi) i1 = c_hi;
    if (i0 >= i1) return;
    bool has4 = lane < 32;
    int cs4m = has4 ? lane + 256 : lane;
    const int ci0 = lane / 9,         si0 = lane % 9;
    const int ci1 = (lane + 64) / 9,  si1 = (lane + 64) % 9;
    const int ci2 = (lane + 128) / 9, si2 = (lane + 128) % 9;
    const int ci3 = (lane + 192) / 9, si3 = (lane + 192) % 9;
    const int ci4 = cs4m / 9,         si4 = cs4m % 9;
    float acc0 = 0.f, acc1 = 0.f, acc2 = 0.f, acc3 = 0.f, acc4 = 0.f;
    for (int i = i0; i < i1; ++i) {
        int snd = snd_s[i];
        const unsigned short* tr = tpw + (size_t)(i - c_lo) * CS;
        float t0 = bf2f(tr[lane]);
        float t1v = bf2f(tr[lane + 64]);
        float t2v = bf2f(tr[lane + 128]);
        float t3v = bf2f(tr[lane + 192]);
        float t4v = bf2f(tr[cs4m]);
        const float* yr = Ys + (size_t)i * 12;
        float y0 = yr[si0], y1 = yr[si1], y2 = yr[si2], y3 = yr[si3], y4 = yr[si4];
        const float* hr = hu + (size_t)snd * C;
        float h0 = hr[ci0], h1 = hr[ci1], h2 = hr[ci2], h3 = hr[ci3], h4 = hr[ci4];
        acc0 += h0 * y0 * t0;
        acc1 += h1 * y1 * t1v;
        acc2 += h2 * y2 * t2v;
        acc3 += h3 * y3 * t3v;
        acc4 += h4 * y4 * t4v;
    }
    float* mrow = msum + (size_t)n * CS;
    mrow[lane] += acc0;
    mrow[lane + 64] += acc1;
    mrow[lane + 128] += acc2;
    mrow[lane + 192] += acc3;
    if (has4) mrow[lane + 256] += acc4;
}

// backward stage A: per edge, stream cs once (row-major tpw):
// gY[s] += gm*hu*tpw; ghu[snd,c] += gm*Y*tpw (L1); gt2[k] += (gm*hu*Y)*W3[k,cs].
template <bool L1>
__global__ __launch_bounds__(128) void k_bwd12(
    const int* __restrict__ snd_s, const int* __restrict__ rcv_s,
    const unsigned short* __restrict__ tpw, const float* __restrict__ Ys,
    const float* __restrict__ gm, const float* __restrict__ hu,
    const float* __restrict__ w3Tg, float* __restrict__ ghu,
    float* __restrict__ GYc, float* __restrict__ GT2c, int c_lo) {
    int tid = threadIdx.x;
    int il = blockIdx.x * 128 + tid;
    int i = c_lo + il;
    int snd = snd_s[i], rcv = rcv_s[i];
    float ysr[S];
#pragma unroll
    for (int s = 0; s < S; ++s) ysr[s] = Ys[(size_t)i * 12 + s];
    float gY[S];
#pragma unroll
    for (int s = 0; s < S; ++s) gY[s] = 0.f;
    float gt2[H];
#pragma unroll
    for (int k = 0; k < H; ++k) gt2[k] = 0.f;
    const float* gmrow = L1 ? gm : (gm + (size_t)rcv * CS);
    const unsigned short* tr = tpw + (size_t)il * CS;
    const float4* w3q = (const float4*)w3Tg;   // [cs][k]
    for (int c = 0; c < C; ++c) {
        float hv = hu[(size_t)snd * C + c];
        float ghc = 0.f;
#pragma unroll
        for (int s = 0; s < S; ++s) {
            int cs = c * 9 + s;
            float gmv = gmrow[cs];
            float yv = ysr[s];
            float tpwv = bf2f(tr[cs]);
            float p = gmv * hv;
            gY[s] += p * tpwv;
            ghc += gmv * yv * tpwv;
            float gtw = p * yv;
#pragma unroll
            for (int k4 = 0; k4 < 16; ++k4) {
                float4 w = w3q[cs * 16 + k4];
                gt2[k4 * 4 + 0] += gtw * w.x;
                gt2[k4 * 4 + 1] += gtw * w.y;
                gt2[k4 * 4 + 2] += gtw * w.z;
                gt2[k4 * 4 + 3] += gtw * w.w;
            }
        }
        if constexpr (L1) atomicAdd(&ghu[(size_t)snd * C + c], ghc);
    }
#pragma unroll
    for (int s = 0; s < S; ++s) GYc[(size_t)il * 12 + s] = gY[s];
#pragma unroll
    for (int k = 0; k < H; ++k) GT2c[(size_t)k * EH + il] = gt2[k];   // coalesced per k
}

// backward stage B: streaming MLP backward (via stored Z2) + geometry + force atomics
__global__ __launch_bounds__(128) void k_mlp_bwd_c(
    const float* __restrict__ pos, const float* __restrict__ shifts,
    const int* __restrict__ perm, const int* __restrict__ snd_s,
    const int* __restrict__ rcv_s, const float* __restrict__ EFs,
    const unsigned short* __restrict__ Z2c, const float* __restrict__ GT2c,
    const float* __restrict__ GYc, const float* __restrict__ w1g,
    const float* __restrict__ w2Tg, float* __restrict__ forces, int c_lo) {
    int tid = threadIdx.x;
    int il = blockIdx.x * 128 + tid;
    int i = c_lo + il;
    int snd = snd_s[i], rcv = rcv_s[i];
    const float4* w2q = (const float4*)w2Tg;   // [k][j]

    float gt1[H];
#pragma unroll
    for (int j = 0; j < H; ++j) gt1[j] = 0.f;
    for (int k = 0; k < H; ++k) {
        float zz = bf2f(Z2c[(size_t)k * EH + il]);
        float g = GT2c[(size_t)k * EH + il];
        float sg = sigm(zz);
        float gz2 = g * sg * (1.f + zz * (1.f - sg));
#pragma unroll
        for (int jj = 0; jj < 16; ++jj) {
            float4 w = w2q[k * 16 + jj];
            gt1[jj * 4 + 0] += gz2 * w.x;
            gt1[jj * 4 + 1] += gz2 * w.y;
            gt1[jj * 4 + 2] += gz2 * w.z;
            gt1[jj * 4 + 3] += gz2 * w.w;
        }
    }
    float ef[NB];
#pragma unroll
    for (int b = 0; b < NB; ++b) ef[b] = EFs[b * E + i];
    float gef[NB];
#pragma unroll
    for (int b = 0; b < NB; ++b) gef[b] = 0.f;
#pragma unroll
    for (int j = 0; j < H; ++j) {
        float z1 = 0.f;
#pragma unroll
        for (int b = 0; b < NB; ++b) z1 += ef[b] * w1g[b * H + j];
        float sg = sigm(z1);
        float gz1 = gt1[j] * sg * (1.f + z1 * (1.f - sg));
#pragma unroll
        for (int b = 0; b < NB; ++b) gef[b] += gz1 * w1g[b * H + j];
    }
    int e = perm[i];
    float vx = pos[rcv * 3 + 0] - pos[snd * 3 + 0] + shifts[e * 3 + 0];
    float vy = pos[rcv * 3 + 1] - pos[snd * 3 + 1] + shifts[e * 3 + 1];
    float vz = pos[rcv * 3 + 2] - pos[snd * 3 + 2] + shifts[e * 3 + 2];
    float r = sqrtf(vx * vx + vy * vy + vz * vz + 1e-12f);
    float inv = 1.0f / r;
    float x = vx * inv, y = vy * inv, z = vz * inv;
    float ru = r * (1.0f / RMAX);
    float env = 0.f, denv_dr = 0.f;
    if (ru < 1.f) {
        float u2 = ru * ru, u4 = u2 * u2, u5 = u4 * ru, u6 = u5 * ru, u7 = u6 * ru, u8 = u7 * ru;
        env = 1.f - 28.f * u6 + 48.f * u7 - 21.f * u8;
        denv_dr = (-168.f * u5 + 336.f * u6 - 168.f * u7) * (1.0f / RMAX);
    }
    float gr = 0.f;
#pragma unroll
    for (int b = 0; b < NB; ++b) {
        float kb = (b + 1) * (PI_F / RMAX);
        float sb = __sinf(kb * r), cb = __cosf(kb * r);
        float bess = BESS_A * sb * inv;
        float dbess = BESS_A * (kb * cb - sb * inv) * inv;
        gr += gef[b] * (dbess * env + bess * denv_dr);
    }
    float gys[S];
#pragma unroll
    for (int s = 0; s < S; ++s) gys[s] = GYc[(size_t)il * 12 + s];
    float gx = C1 * gys[1] + C2 * y * gys[4] + C2 * z * gys[7] + C2 * x * gys[8];
    float gy = C1 * gys[2] + C2 * x * gys[4] + C2 * z * gys[5] - C2 * y * gys[8];
    float gz = C1 * gys[3] + C2 * y * gys[5] + 6.f * C3 * z * gys[6] + C2 * x * gys[7];
    float dot = gx * x + gy * y + gz * z;
    float gvx = (gx - dot * x) * inv + gr * x;
    float gvy = (gy - dot * y) * inv + gr * y;
    float gvz = (gz - dot * z) * inv + gr * z;
    atomicAdd(&forces[snd * 3 + 0], gvx);
    atomicAdd(&forces[snd * 3 + 1], gvy);
    atomicAdd(&forces[snd * 3 + 2], gvz);
    atomicAdd(&forces[rcv * 3 + 0], -gvx);
    atomicAdd(&forces[rcv * 3 + 1], -gvy);
    atomicAdd(&forces[rcv * 3 + 2], -gvz);
}

} // namespace

extern "C" void kernel_launch(void* const* d_in, const int* in_sizes, int n_in,
                              void* d_out, int out_size, void* d_ws, size_t ws_size,
                              hipStream_t stream) {
    const float* pos    = (const float*)d_in[0];
    const float* attrs  = (const float*)d_in[1];
    const float* shifts = (const float*)d_in[2];
    const float* ae     = (const float*)d_in[3];
    const float* Wemb   = (const float*)d_in[4];
    const float* Wup    = (const float*)d_in[5];
    const float* Wm1    = (const float*)d_in[6];
    const float* Wm2    = (const float*)d_in[7];
    const float* Wm3    = (const float*)d_in[8];
    const float* Wlin   = (const float*)d_in[9];
    const float* Wskip  = (const float*)d_in[10];
    const float* Wprod  = (const float*)d_in[11];
    const float* Wread  = (const float*)d_in[12];
    const float* scale  = (const float*)d_in[13];
    const float* shiftp = (const float*)d_in[14];
    const int*   eidx   = (const int*)d_in[15];
    const int*   batch  = (const int*)d_in[16];

    float* out       = (float*)d_out;
    float* out_tot   = out;                     // G
    float* out_ne    = out + G;                 // N
    float* out_ie    = out + G + N;             // G
    float* out_F     = out + 2 * G + N;         // N*3
    float* out_feats = out + 2 * G + N + 3 * N; // N*2C

    char* w = (char*)d_ws;
    auto alloc = [&](size_t bytes) { void* p = (void*)w; w += (bytes + 255) & ~(size_t)255; return p; };
    int*   sp     = (int*)alloc((size_t)N * 4);
    float* ne0    = (float*)alloc((size_t)N * 4);
    float* es     = (float*)alloc((size_t)N * 4);
    float* e0g    = (float*)alloc((size_t)G * 4);
    float* ieg    = (float*)alloc((size_t)G * 4);
    float* h0     = (float*)alloc((size_t)N * C * 4);
    float* h1     = (float*)alloc((size_t)N * C * 4);
    float* hu0    = (float*)alloc((size_t)N * C * 4);
    float* hu1    = (float*)alloc((size_t)N * C * 4);
    float* msgb   = (float*)alloc((size_t)N * C * 4);
    float* ghu1   = (float*)alloc((size_t)N * C * 4);
    float* gh1    = (float*)alloc((size_t)N * C * 4);
    float* gms1   = (float*)alloc((size_t)CS * 4);
    float* gskip1 = (float*)alloc((size_t)Z * C * 4);
    int*   cnt    = (int*)alloc((size_t)N * 4);
    int*   rowst  = (int*)alloc((size_t)(N + 1) * 4);
    int*   posb   = (int*)alloc((size_t)N * 4);
    int*   perm   = (int*)alloc((size_t)E * 4);
    int*   snd_s  = (int*)alloc((size_t)E * 4);
    int*   rcv_s  = (int*)alloc((size_t)E * 4);
    float* msum   = (float*)alloc((size_t)N * CS * 4);     // fwd msgsum / bwd gm0
    float* EFs    = (float*)alloc((size_t)NB * E * 4);
    float* Ys     = (float*)alloc((size_t)E * 12 * 4);
    float* w2T    = (float*)alloc((size_t)2 * H * H * 4);
    float* w3T    = (float*)alloc((size_t)2 * CS * H * 4);
    unsigned short* tpw = (unsigned short*)alloc((size_t)EH * CS * 2);   // 92.2 MB
    unsigned short* Z2c = (unsigned short*)alloc((size_t)EH * H * 2);    // 20.5 MB
    float* GT2c  = (float*)alloc((size_t)EH * H * 4);                    // 41.0 MB
    float* GYc   = (float*)alloc((size_t)EH * 12 * 4);                   // 7.7 MB

    hipMemsetAsync(es, 0, (size_t)N * 4, stream);
    hipMemsetAsync(e0g, 0, (size_t)G * 4, stream);
    hipMemsetAsync(ieg, 0, (size_t)G * 4, stream);
    hipMemsetAsync(ghu1, 0, (size_t)N * C * 4, stream);
    hipMemsetAsync(cnt, 0, (size_t)N * 4, stream);
    hipMemsetAsync(out_F, 0, (size_t)N * 3 * 4, stream);

    dim3 b256(256);
    int gn    = (N + 255) / 256;
    int gnc   = (N * C + 255) / 256;
    int gncs  = (N * CS + 255) / 256;
    int ge    = E / 256;                 // 1250, exact
    int geh   = EH / 256;                // 625, exact (mlp_tpw)
    int geh1  = EH / 128;                // 1250, exact (bwd12 / mlp_bwd_c)
    int gg    = N / 8;                   // 2500, exact

    // CSR build (receiver-sorted)
    k_csr_count<<<ge, b256, 0, stream>>>(eidx, cnt);
    k_csr_scan<<<1, 1024, 0, stream>>>(cnt, rowst, posb);
    k_csr_fill<<<ge, b256, 0, stream>>>(eidx, posb, perm, snd_s, rcv_s);

    k_node_init<<<gn, b256, 0, stream>>>(attrs, ae, Wemb, batch, sp, ne0, h0, e0g);
    k_prep<<<176, b256, 0, stream>>>(Wm2, Wm3, w2T, w3T);
    k_geom<<<ge, b256, 0, stream>>>(pos, shifts, perm, snd_s, rcv_s, Ys, EFs);

    // ---- layer 0 forward ----
    k_matmul_CC<<<gnc, b256, 0, stream>>>(h0, Wup, hu0);
    hipMemsetAsync(msum, 0, (size_t)N * CS * 4, stream);
    for (int cchunk = 0; cchunk < 2; ++cchunk) {
        int lo = cchunk * EH, hi = lo + EH;
        k_mlp_tpw<<<geh, b256, 0, stream>>>(EFs, Wm1, w2T, w3T, lo, tpw, Z2c);
        k_gather<<<gg, 512, 0, stream>>>(rowst, snd_s, hu0, tpw, Ys, msum, lo, hi);
    }
    k_msg<<<gnc, b256, 0, stream>>>(msum, Wlin, msgb);
    k_node_h<1><<<gn, b256, 0, stream>>>(msgb, h0, sp, Wprod, Wskip, Wread, h1, es, out_feats);

    // ---- layer 1 forward + fused layer-1 backward (gms1 is input-independent) ----
    k_matmul_CC<<<gnc, b256, 0, stream>>>(h1, Wup + C * C, hu1);
    k_const1<<<1, 512, 0, stream>>>(Wread + C, Wprod + C * C, Wlin + CS * C,
                                    Wskip + Z * C * C, scale, gms1, gskip1);
    hipMemsetAsync(msum, 0, (size_t)N * CS * 4, stream);
    for (int cchunk = 0; cchunk < 2; ++cchunk) {
        int lo = cchunk * EH, hi = lo + EH;
        k_mlp_tpw<<<geh, b256, 0, stream>>>(EFs, Wm1 + NB * H, w2T + H * H, w3T + CS * H,
                                            lo, tpw, Z2c);
        k_gather<<<gg, 512, 0, stream>>>(rowst, snd_s, hu1, tpw, Ys, msum, lo, hi);
        k_bwd12<true><<<geh1, 128, 0, stream>>>(snd_s, rcv_s, tpw, Ys, gms1, hu1,
                                                w3T + CS * H, ghu1, GYc, GT2c, lo);
        k_mlp_bwd_c<<<geh1, 128, 0, stream>>>(pos, shifts, perm, snd_s, rcv_s, EFs, Z2c,
                                              GT2c, GYc, Wm1 + NB * H, w2T + H * H,
                                              out_F, lo);
    }
    k_msg<<<gnc, b256, 0, stream>>>(msum, Wlin + CS * C, msgb);
    k_node_h<0><<<gn, b256, 0, stream>>>(msgb, h1, sp, Wprod + C * C, Wskip + Z * C * C,
                                         Wread + C, nullptr, es, out_feats + C);

    // ---- energies ----
    k_finalize<<<gn, b256, 0, stream>>>(ne0, es, scale, shiftp, batch, out_ne, ieg);
    k_graph<<<1, G, 0, stream>>>(e0g, ieg, out_tot, out_ie);

    // ---- chain to layer 0 ----
    k_gh1<<<gnc, b256, 0, stream>>>(Wread, gskip1, sp, ghu1, Wup + C * C, scale, gh1);
    k_gmsg<<<gnc, b256, 0, stream>>>(gh1, Wprod, msgb);
    k_gmsum<<<gncs, b256, 0, stream>>>(msgb, Wlin, msum);   // msum <- gm0

    // ---- layer 0 backward (chunked recompute of tpw/Z2) ----
    for (int cchunk = 0; cchunk < 2; ++cchunk) {
        int lo = cchunk * EH;
        k_mlp_tpw<<<geh, b256, 0, stream>>>(EFs, Wm1, w2T, w3T, lo, tpw, Z2c);
        k_bwd12<false><<<geh1, 128, 0, stream>>>(snd_s, rcv_s, tpw, Ys, msum, hu0,
                                                 w3T, nullptr, GYc, GT2c, lo);
        k_mlp_bwd_c<<<geh1, 128, 0, stream>>>(pos, shifts, perm, snd_s, rcv_s, EFs, Z2c,
                                              GT2c, GYc, Wm1, w2T, out_F, lo);
    }

    (void)in_sizes; (void)n_in; (void)out_size; (void)ws_size; (void)eidx;
}